// Round 8
// baseline (1479.393 us; speedup 1.0000x reference)
//
#include <hip/hip_runtime.h>
#include <math.h>

#define BB 8
#define NN 325
#define TT 24
#define DD 64
#define HH 8
#define MM 16
#define E2 128
#define DK 16
#define NEG 0.1f
#define NNODE (BB * NN)          // 2600

typedef short bf16x8 __attribute__((ext_vector_type(8)));
typedef float f32x4 __attribute__((ext_vector_type(4)));

__device__ __forceinline__ unsigned short f2bf(float f) {
    union { float f; unsigned u; } v; v.f = f;
    unsigned r = v.u + 0x7fffu + ((v.u >> 16) & 1u);   // RNE
    return (unsigned short)(r >> 16);
}
__device__ __forceinline__ unsigned packbf(float a, float b) {
    return (unsigned)f2bf(a) | ((unsigned)f2bf(b) << 16);
}
__device__ __forceinline__ float bflo(unsigned u) { return __uint_as_float(u << 16); }
__device__ __forceinline__ float bfhi(unsigned u) { return __uint_as_float(u & 0xffff0000u); }

__device__ __forceinline__ bf16x8 pack_bf8(float4 lo, float4 hi) {
    bf16x8 r;
    r[0] = (short)f2bf(lo.x); r[1] = (short)f2bf(lo.y);
    r[2] = (short)f2bf(lo.z); r[3] = (short)f2bf(lo.w);
    r[4] = (short)f2bf(hi.x); r[5] = (short)f2bf(hi.y);
    r[6] = (short)f2bf(hi.z); r[7] = (short)f2bf(hi.w);
    return r;
}

// ---------------- K1: tfeat[b][m] = tanh(mean_t(tXin[b,0,t,:]) @ tproj_w + tproj_b)
__global__ void k_tfeat(const float* __restrict__ tXin, const float* __restrict__ tproj_w,
                        const float* __restrict__ tproj_b, float* __restrict__ tfeat) {
    int b = blockIdx.x;
    int d = threadIdx.x;  // 64 threads
    __shared__ float mv[DD];
    float a = 0.f;
    for (int t = 0; t < TT; ++t)
        a += tXin[((size_t)(b * NN + 0) * TT + t) * DD + d];
    mv[d] = a * (1.f / (float)TT);
    __syncthreads();
    if (d < MM) {
        float acc = tproj_b[d];
        for (int j = 0; j < DD; ++j) acc += mv[j] * tproj_w[j * MM + d];
        tfeat[b * MM + d] = tanhf(acc);
    }
}

// ---------------- K2: support = einsum('btnm,bmtd->bntd'); gcn_out = relu(support@gcn_w + b)
#define TN 64
__global__ __launch_bounds__(256) void k_gcn(const float* __restrict__ matrix,
                                             const float* __restrict__ hidden,
                                             const float* __restrict__ gcn_w,
                                             const float* __restrict__ gcn_b,
                                             float* __restrict__ gcn_out) {
    int bt = blockIdx.x;
    int tile = blockIdx.y;
    int b = bt / TT, t = bt % TT;
    int n0 = tile * TN;

    __shared__ float s_mat[TN][68];
    __shared__ float s_H[64][DD];
    __shared__ float s_gw[DD][DD];

    int tid = threadIdx.x;
    for (int idx = tid; idx < DD * DD; idx += 256)
        s_gw[idx / DD][idx % DD] = gcn_w[idx];

    int r  = tid >> 3;
    int d0 = (tid & 7) << 3;
    float acc0[8], acc1[8];
#pragma unroll
    for (int i = 0; i < 8; ++i) { acc0[i] = 0.f; acc1[i] = 0.f; }

    for (int m0 = 0; m0 < NN; m0 += 64) {
        __syncthreads();
        for (int idx = tid; idx < TN * 64; idx += 256) {
            int rr = idx >> 6, cc = idx & 63;
            int n = n0 + rr, m = m0 + cc;
            s_mat[rr][cc] = (n < NN && m < NN) ? matrix[((size_t)(b * TT + t) * NN + n) * NN + m] : 0.f;
        }
        for (int idx = tid; idx < 64 * DD; idx += 256) {
            int mm = idx >> 6, d = idx & 63;
            int m = m0 + mm;
            s_H[mm][d] = (m < NN) ? hidden[((size_t)(b * NN + m) * TT + t) * DD + d] : 0.f;
        }
        __syncthreads();
        int mmax = (NN - m0 < 64) ? (NN - m0) : 64;
        for (int mm = 0; mm < mmax; ++mm) {
            float w0 = s_mat[r][mm];
            float w1 = s_mat[r + 32][mm];
            float4 h0 = *(const float4*)&s_H[mm][d0];
            float4 h1 = *(const float4*)&s_H[mm][d0 + 4];
            acc0[0] += w0 * h0.x; acc0[1] += w0 * h0.y; acc0[2] += w0 * h0.z; acc0[3] += w0 * h0.w;
            acc0[4] += w0 * h1.x; acc0[5] += w0 * h1.y; acc0[6] += w0 * h1.z; acc0[7] += w0 * h1.w;
            acc1[0] += w1 * h0.x; acc1[1] += w1 * h0.y; acc1[2] += w1 * h0.z; acc1[3] += w1 * h0.w;
            acc1[4] += w1 * h1.x; acc1[5] += w1 * h1.y; acc1[6] += w1 * h1.z; acc1[7] += w1 * h1.w;
        }
    }

    __syncthreads();
    *(float4*)&s_H[r][d0]          = make_float4(acc0[0], acc0[1], acc0[2], acc0[3]);
    *(float4*)&s_H[r][d0 + 4]      = make_float4(acc0[4], acc0[5], acc0[6], acc0[7]);
    *(float4*)&s_H[r + 32][d0]     = make_float4(acc1[0], acc1[1], acc1[2], acc1[3]);
    *(float4*)&s_H[r + 32][d0 + 4] = make_float4(acc1[4], acc1[5], acc1[6], acc1[7]);
    __syncthreads();

    float g0[8], g1[8];
#pragma unroll
    for (int i = 0; i < 8; ++i) { g0[i] = gcn_b[d0 + i]; g1[i] = g0[i]; }
    for (int d = 0; d < DD; ++d) {
        float s0 = s_H[r][d], s1 = s_H[r + 32][d];
        float4 w0 = *(const float4*)&s_gw[d][d0];
        float4 w1 = *(const float4*)&s_gw[d][d0 + 4];
        g0[0] += s0 * w0.x; g0[1] += s0 * w0.y; g0[2] += s0 * w0.z; g0[3] += s0 * w0.w;
        g0[4] += s0 * w1.x; g0[5] += s0 * w1.y; g0[6] += s0 * w1.z; g0[7] += s0 * w1.w;
        g1[0] += s1 * w0.x; g1[1] += s1 * w0.y; g1[2] += s1 * w0.z; g1[3] += s1 * w0.w;
        g1[4] += s1 * w1.x; g1[5] += s1 * w1.y; g1[6] += s1 * w1.z; g1[7] += s1 * w1.w;
    }
#pragma unroll
    for (int i = 0; i < 8; ++i) {
        g0[i] = g0[i] > 0.f ? g0[i] : 0.f;
        g1[i] = g1[i] > 0.f ? g1[i] : 0.f;
    }
    if (n0 + r < NN) {
        size_t base = ((size_t)(b * NN + (n0 + r)) * TT + t) * DD;
        *(float4*)&gcn_out[base + d0]     = make_float4(g0[0], g0[1], g0[2], g0[3]);
        *(float4*)&gcn_out[base + d0 + 4] = make_float4(g0[4], g0[5], g0[6], g0[7]);
    }
    if (n0 + r + 32 < NN) {
        size_t base = ((size_t)(b * NN + (n0 + r + 32)) * TT + t) * DD;
        *(float4*)&gcn_out[base + d0]     = make_float4(g1[0], g1[1], g1[2], g1[3]);
        *(float4*)&gcn_out[base + d0 + 4] = make_float4(g1[4], g1[5], g1[6], g1[7]);
    }
}

// ---------------- K3a: Wp = sum_m e[m]*W[m], stored bf16 in MFMA B-fragment-major layout:
// per (node, p): u16[nt(8)][ks(4)][lane(64)][j(8)]; element (i,k) -> nt=k>>4, ks=i>>5,
// lane=(k&15)|(((i>>3)&3)<<4), j=i&7.  grid (ceil(Uc/16), 48); block 256.
__global__ __launch_bounds__(256) void k_wp(
    const float* __restrict__ node_emb, const float* __restrict__ tfeat,
    const float* __restrict__ WQ, const float* __restrict__ WK, const float* __restrict__ WV,
    unsigned short* __restrict__ wp, int u0, int Uc) {
    int un0 = blockIdx.x * 16;
    int chunk = blockIdx.y;                 // 0..47
    int p = chunk >> 4;                     // 0=Q 1=K 2=V
    int off = (chunk & 15) << 10;           // 1024-elem chunk within 16384
    int tid = threadIdx.x;
    const float* __restrict__ W = (p == 0) ? WQ : ((p == 1) ? WK : WV);

    __shared__ float s_e[16][MM];
    {
        int nn = tid >> 4, m = tid & 15;    // 256 = 16*16 exactly
        int us = un0 + nn;
        float e = 0.f;
        if (us < Uc) {
            int u = u0 + us;
            int b = u / NN, n = u % NN;
            e = node_emb[n * MM + m] * tfeat[b * MM + m];
        }
        s_e[nn][m] = e;
    }
    __syncthreads();

    int j = off + tid * 4;                  // flat [i][k], k contiguous
    int i  = j >> 7;                        // input-dim row 0..127
    int k0 = j & 127;                       // output col, 4-aligned
    float4 acc[16];
#pragma unroll
    for (int nn = 0; nn < 16; ++nn) acc[nn] = make_float4(0.f, 0.f, 0.f, 0.f);
#pragma unroll
    for (int m = 0; m < MM; ++m) {
        float4 w = *(const float4*)&W[(size_t)m * 16384 + j];
#pragma unroll
        for (int nn = 0; nn < 16; ++nn) {
            float e = s_e[nn][m];
            acc[nn].x += e * w.x; acc[nn].y += e * w.y;
            acc[nn].z += e * w.z; acc[nn].w += e * w.w;
        }
    }

    // fragment store offsets (same for all 16 nodes)
    int ks = i >> 5;
    int jf = i & 7;
    int lhi = ((i >> 3) & 3) << 4;
    int nt = k0 >> 4;                       // k0..k0+3 share nt (k0 4-aligned)
    int fbase = p * 16384 + ((nt * 4 + ks) * 64) * 8 + jf;
    int foff[4];
#pragma unroll
    for (int c = 0; c < 4; ++c)
        foff[c] = fbase + ((((k0 + c) & 15) | lhi) << 3);

#pragma unroll
    for (int nn = 0; nn < 16; ++nn) {
        int us = un0 + nn;
        if (us < Uc) {
            unsigned short* dst = wp + (size_t)us * 49152;
            dst[foff[0]] = f2bf(acc[nn].x);
            dst[foff[1]] = f2bf(acc[nn].y);
            dst[foff[2]] = f2bf(acc[nn].z);
            dst[foff[3]] = f2bf(acc[nn].w);
        }
    }
}

// ---------------- K3b (fused): per node: MFMA proj -> attention -> out-proj -> gate -> residual
// 256 threads (4 waves). LDS ~48 KB -> 3 blocks/CU. waves_per_eu(2) caps VGPR at 128;
// p-loop NOT unrolled so only one projection's loads+accs are live (~100 regs peak).
#define QKS 66
#define QKP (TT * QKS)          // 1584 u32 per proj plane
#define SC_OFF 4752
#define VAL_OFF 7248
__global__ __launch_bounds__(256)
__attribute__((amdgpu_waves_per_eu(2)))
void k_fuse(
    const float* __restrict__ hidden, const float* __restrict__ tXin,
    const unsigned short* __restrict__ wp,
    const float* __restrict__ out_w, const float* __restrict__ out_b,
    const float* __restrict__ gate_w, const float* __restrict__ gate_b,
    const float* __restrict__ gcn_out, float* __restrict__ out,
    int u0) {
    int us = blockIdx.x;
    int u = u0 + us;
    int tid = threadIdx.x;

    __shared__ __align__(16) unsigned arena[8832];
    __shared__ float s_gcn[TT][68];
    __shared__ float s_value[TT][68];

    size_t base = (size_t)u * TT * DD;

    // ---- gcn staging (no sync needed until attention barrier)
    for (int idx = tid; idx < TT * DD; idx += 256)
        s_gcn[idx >> 6][idx & 63] = gcn_out[base + idx];

    // ---- A fragments: x = [hidden | tXin] rows, bf16. A[t][i]: t=lane&15 (+16), i=ks*32+(lane>>4)*8+j
    int lane = tid & 63, wid = tid >> 6;
    int trow = lane & 15, kgrp = lane >> 4;
    bf16x8 afrag[2][4];
#pragma unroll
    for (int mt = 0; mt < 2; ++mt) {
        int t = mt * 16 + trow;
        bool valid = (t < TT);
#pragma unroll
        for (int ks = 0; ks < 4; ++ks) {
            int i0 = ks * 32 + kgrp * 8;
            float4 lo = make_float4(0.f, 0.f, 0.f, 0.f), hi = lo;
            if (valid) {
                const float* src = (i0 < DD) ? &hidden[base + t * DD + i0]
                                             : &tXin[base + t * DD + (i0 - DD)];
                lo = *(const float4*)src;
                hi = *(const float4*)(src + 4);
            }
            afrag[mt][ks] = pack_bf8(lo, hi);
        }
    }

    // ---- proj: C[t][k] = x @ Wp via MFMA; wave w owns n-tiles {w, w+4}
    const unsigned short* wbase = wp + (size_t)us * 49152;
    unsigned short* q16 = (unsigned short*)arena;
    int rowg = kgrp * 4;
    int col0 = wid * 16 + (lane & 15);
    int col1 = (wid + 4) * 16 + (lane & 15);
#pragma unroll 1
    for (int p = 0; p < 3; ++p) {
        f32x4 acc00 = {0.f, 0.f, 0.f, 0.f}, acc01 = acc00, acc10 = acc00, acc11 = acc00;
#pragma unroll
        for (int ks = 0; ks < 4; ++ks) {
            union { uint4 u4; bf16x8 v; } c0, c1;
            c0.u4 = *(const uint4*)(wbase + (size_t)p * 16384 + (((wid) * 4 + ks) * 64 + lane) * 8);
            c1.u4 = *(const uint4*)(wbase + (size_t)p * 16384 + (((wid + 4) * 4 + ks) * 64 + lane) * 8);
            acc00 = __builtin_amdgcn_mfma_f32_16x16x32_bf16(afrag[0][ks], c0.v, acc00, 0, 0, 0);
            acc10 = __builtin_amdgcn_mfma_f32_16x16x32_bf16(afrag[1][ks], c0.v, acc10, 0, 0, 0);
            acc01 = __builtin_amdgcn_mfma_f32_16x16x32_bf16(afrag[0][ks], c1.v, acc01, 0, 0, 0);
            acc11 = __builtin_amdgcn_mfma_f32_16x16x32_bf16(afrag[1][ks], c1.v, acc11, 0, 0, 0);
        }
        // C write: row=(lane>>4)*4+r (+16 for mt1), col=nt*16+(lane&15); lrelu; bf16 into qkv
#pragma unroll
        for (int r = 0; r < 4; ++r) {
            int t = rowg + r;
            float v0 = acc00[r]; v0 = (v0 >= 0.f) ? v0 : NEG * v0;
            float v1 = acc01[r]; v1 = (v1 >= 0.f) ? v1 : NEG * v1;
            q16[(p * QKP + t * QKS) * 2 + col0] = f2bf(v0);
            q16[(p * QKP + t * QKS) * 2 + col1] = f2bf(v1);
        }
        if (rowg < 8) {
#pragma unroll
            for (int r = 0; r < 4; ++r) {
                int t = 16 + rowg + r;
                float v0 = acc10[r]; v0 = (v0 >= 0.f) ? v0 : NEG * v0;
                float v1 = acc11[r]; v1 = (v1 >= 0.f) ? v1 : NEG * v1;
                q16[(p * QKP + t * QKS) * 2 + col0] = f2bf(v0);
                q16[(p * QKP + t * QKS) * 2 + col1] = f2bf(v1);
            }
        }
    }
    unsigned* s_qkv = arena;
    __syncthreads();

    // ---- phase C1: scores w[h][t][s] = exp(scale * q.k) for s<=t, 0 otherwise (packed pairs)
    unsigned* s_sc = arena + SC_OFF;
    if (tid < HH * TT) {
        int h = tid / TT, t = tid % TT;
        const float scale = 0.25f;
        float qf[16];
#pragma unroll
        for (int j = 0; j < 8; ++j) {
            unsigned uq = s_qkv[0 * QKP + t * QKS + 8 * h + j];
            qf[2 * j] = bflo(uq); qf[2 * j + 1] = bfhi(uq);
        }
#pragma unroll
        for (int s2 = 0; s2 < 12; ++s2) {
            int s0 = 2 * s2;
            float d0 = 0.f, d1 = 0.f;
#pragma unroll
            for (int j = 0; j < 8; ++j) {
                unsigned ka = s_qkv[1 * QKP + s0 * QKS + 8 * h + j];
                unsigned kb = s_qkv[1 * QKP + (s0 + 1) * QKS + 8 * h + j];
                d0 += qf[2 * j] * bflo(ka) + qf[2 * j + 1] * bfhi(ka);
                d1 += qf[2 * j] * bflo(kb) + qf[2 * j + 1] * bfhi(kb);
            }
            float w0 = (s0 <= t) ? __expf(d0 * scale) : 0.f;
            float w1 = (s0 + 1 <= t) ? __expf(d1 * scale) : 0.f;
            s_sc[(h * TT + t) * 13 + s2] = packbf(w0, w1);
        }
    }
    __syncthreads();

    // ---- phase C2: normalize + PV -> packed val[24][66]
    unsigned* s_val = arena + VAL_OFF;
#pragma unroll
    for (int it = 0; it < 3; ++it) {
        int item = tid + it * 256;             // < 768
        int h = item / 96;
        int r = item % 96;
        int t = r >> 2, d4 = r & 3;
        int kg0 = 8 * h + 2 * d4;
        float sum = 0.f, v0 = 0.f, v1 = 0.f, v2 = 0.f, v3 = 0.f;
#pragma unroll
        for (int s2 = 0; s2 < 12; ++s2) {
            unsigned uw = s_sc[(h * TT + t) * 13 + s2];
            float w0 = bflo(uw), w1 = bfhi(uw);
            sum += w0 + w1;
            unsigned ua = s_qkv[2 * QKP + (2 * s2) * QKS + kg0];
            unsigned ub = s_qkv[2 * QKP + (2 * s2) * QKS + kg0 + 1];
            v0 += w0 * bflo(ua); v1 += w0 * bfhi(ua);
            v2 += w0 * bflo(ub); v3 += w0 * bfhi(ub);
            unsigned uc = s_qkv[2 * QKP + (2 * s2 + 1) * QKS + kg0];
            unsigned ud = s_qkv[2 * QKP + (2 * s2 + 1) * QKS + kg0 + 1];
            v0 += w1 * bflo(uc); v1 += w1 * bfhi(uc);
            v2 += w1 * bflo(ud); v3 += w1 * bfhi(ud);
        }
        float inv = 1.f / sum;
        s_val[t * QKS + kg0]     = packbf(v0 * inv, v1 * inv);
        s_val[t * QKS + kg0 + 1] = packbf(v2 * inv, v3 * inv);
    }
    __syncthreads();

    // ---- phase D: value = lrelu(val @ out_w + out_b)
    for (int o = tid; o < TT * 16; o += 256) {
        int tq = o >> 4;
        int dd0 = (o & 15) * 4;
        float4 a = *(const float4*)&out_b[dd0];
        for (int j0 = 0; j0 < E2; j0 += 4) {
            unsigned xa = s_val[tq * QKS + j0 / 2];
            unsigned xb = s_val[tq * QKS + j0 / 2 + 1];
            float x0 = bflo(xa), x1 = bfhi(xa), x2 = bflo(xb), x3 = bfhi(xb);
            const float4 w0 = *(const float4*)&out_w[(j0 + 0) * DD + dd0];
            const float4 w1 = *(const float4*)&out_w[(j0 + 1) * DD + dd0];
            const float4 w2 = *(const float4*)&out_w[(j0 + 2) * DD + dd0];
            const float4 w3 = *(const float4*)&out_w[(j0 + 3) * DD + dd0];
            a.x += x0 * w0.x + x1 * w1.x + x2 * w2.x + x3 * w3.x;
            a.y += x0 * w0.y + x1 * w1.y + x2 * w2.y + x3 * w3.y;
            a.z += x0 * w0.z + x1 * w1.z + x2 * w2.z + x3 * w3.z;
            a.w += x0 * w0.w + x1 * w1.w + x2 * w2.w + x3 * w3.w;
        }
        a.x = (a.x >= 0.f) ? a.x : NEG * a.x;
        a.y = (a.y >= 0.f) ? a.y : NEG * a.y;
        a.z = (a.z >= 0.f) ? a.z : NEG * a.z;
        a.w = (a.w >= 0.f) ? a.w : NEG * a.w;
        *(float4*)&s_value[tq][dd0] = a;
    }
    __syncthreads();

    // ---- phase E: gate + residual
    for (int o = tid; o < TT * 16; o += 256) {
        int tq = o >> 4;
        int dd0 = (o & 15) * 4;
        float4 zz = *(const float4*)&gate_b[dd0];
        for (int j0 = 0; j0 < DD; j0 += 4) {
            const float4 x = *(const float4*)&s_gcn[tq][j0];
            const float4 w0 = *(const float4*)&gate_w[(j0 + 0) * DD + dd0];
            const float4 w1 = *(const float4*)&gate_w[(j0 + 1) * DD + dd0];
            const float4 w2 = *(const float4*)&gate_w[(j0 + 2) * DD + dd0];
            const float4 w3 = *(const float4*)&gate_w[(j0 + 3) * DD + dd0];
            zz.x += x.x * w0.x + x.y * w1.x + x.z * w2.x + x.w * w3.x;
            zz.y += x.x * w0.y + x.y * w1.y + x.z * w2.y + x.w * w3.y;
            zz.z += x.x * w0.z + x.y * w1.z + x.z * w2.z + x.w * w3.z;
            zz.w += x.x * w0.w + x.y * w1.w + x.z * w2.w + x.w * w3.w;
        }
        for (int j0 = 0; j0 < DD; j0 += 4) {
            const float4 x = *(const float4*)&s_value[tq][j0];
            const float4 w0 = *(const float4*)&gate_w[(DD + j0 + 0) * DD + dd0];
            const float4 w1 = *(const float4*)&gate_w[(DD + j0 + 1) * DD + dd0];
            const float4 w2 = *(const float4*)&gate_w[(DD + j0 + 2) * DD + dd0];
            const float4 w3 = *(const float4*)&gate_w[(DD + j0 + 3) * DD + dd0];
            zz.x += x.x * w0.x + x.y * w1.x + x.z * w2.x + x.w * w3.x;
            zz.y += x.x * w0.y + x.y * w1.y + x.z * w2.y + x.w * w3.y;
            zz.z += x.x * w0.z + x.y * w1.z + x.z * w2.z + x.w * w3.z;
            zz.w += x.x * w0.w + x.y * w1.w + x.z * w2.w + x.w * w3.w;
        }
        size_t ob = base + tq * DD + dd0;
        const float4 hv = *(const float4*)&hidden[ob];
        const float4 gv = *(const float4*)&s_gcn[tq][dd0];
        const float4 vv = *(const float4*)&s_value[tq][dd0];
        float4 oo;
        float z;
        z = 1.f / (1.f + __expf(-zz.x)); oo.x = z * gv.x + (1.f - z) * vv.x + hv.x;
        z = 1.f / (1.f + __expf(-zz.y)); oo.y = z * gv.y + (1.f - z) * vv.y + hv.y;
        z = 1.f / (1.f + __expf(-zz.z)); oo.z = z * gv.z + (1.f - z) * vv.z + hv.z;
        z = 1.f / (1.f + __expf(-zz.w)); oo.w = z * gv.w + (1.f - z) * vv.w + hv.w;
        *(float4*)&out[ob] = oo;
    }
}

extern "C" void kernel_launch(void* const* d_in, const int* in_sizes, int n_in,
                              void* d_out, int out_size, void* d_ws, size_t ws_size,
                              hipStream_t stream) {
    const float* hidden   = (const float*)d_in[0];
    const float* tXin     = (const float*)d_in[1];
    const float* matrix   = (const float*)d_in[2];
    const float* gcn_w    = (const float*)d_in[3];
    const float* gcn_b    = (const float*)d_in[4];
    const float* node_emb = (const float*)d_in[5];
    const float* tproj_w  = (const float*)d_in[6];
    const float* tproj_b  = (const float*)d_in[7];
    const float* WK_      = (const float*)d_in[8];   // dict order: WK, WQ, WV
    const float* WQ_      = (const float*)d_in[9];
    const float* WV_      = (const float*)d_in[10];
    const float* out_w    = (const float*)d_in[11];
    const float* out_b    = (const float*)d_in[12];
    const float* gate_w   = (const float*)d_in[13];
    const float* gate_b   = (const float*)d_in[14];
    float* out = (float*)d_out;

    char* ws = (char*)d_ws;
    float* tfeat   = (float*)ws;                         // 512 B
    float* gcn_out = (float*)(ws + 512);                 // 15,974,400 B
    size_t off_wp  = 512 + (size_t)BB * NN * TT * DD * 4;

    const size_t per_wp = 3 * (size_t)E2 * E2 * 2;       // 98304 B per node (bf16)
    long long avail = (long long)ws_size - (long long)off_wp;
    long long Ull = avail / (long long)per_wp;
    int U = (Ull < 1) ? 1 : ((Ull > NNODE) ? NNODE : (int)Ull);

    unsigned short* wp_buf = (unsigned short*)(ws + off_wp);

    k_tfeat<<<BB, DD, 0, stream>>>(tXin, tproj_w, tproj_b, tfeat);
    k_gcn<<<dim3(BB * TT, (NN + TN - 1) / TN), 256, 0, stream>>>(matrix, hidden, gcn_w, gcn_b, gcn_out);

    for (int u0 = 0; u0 < NNODE; u0 += U) {
        int Uc = (NNODE - u0 < U) ? (NNODE - u0) : U;
        k_wp<<<dim3((Uc + 15) / 16, 48), 256, 0, stream>>>(node_emb, tfeat, WQ_, WK_, WV_,
                                                           wp_buf, u0, Uc);
        k_fuse<<<Uc, 256, 0, stream>>>(hidden, tXin, wp_buf, out_w, out_b,
                                       gate_w, gate_b, gcn_out, out, u0);
    }
}

// Round 9
// 711.426 us; speedup vs baseline: 2.0795x; 2.0795x over previous
//
#include <hip/hip_runtime.h>
#include <math.h>

#define BB 8
#define NN 325
#define TT 24
#define DD 64
#define HH 8
#define MM 16
#define E2 128
#define DK 16
#define NEG 0.1f
#define NNODE (BB * NN)          // 2600

typedef short bf16x8 __attribute__((ext_vector_type(8)));
typedef float f32x4 __attribute__((ext_vector_type(4)));

__device__ __forceinline__ unsigned short f2bf(float f) {
    union { float f; unsigned u; } v; v.f = f;
    unsigned r = v.u + 0x7fffu + ((v.u >> 16) & 1u);   // RNE
    return (unsigned short)(r >> 16);
}
__device__ __forceinline__ unsigned packbf(float a, float b) {
    return (unsigned)f2bf(a) | ((unsigned)f2bf(b) << 16);
}
__device__ __forceinline__ float bflo(unsigned u) { return __uint_as_float(u << 16); }
__device__ __forceinline__ float bfhi(unsigned u) { return __uint_as_float(u & 0xffff0000u); }

__device__ __forceinline__ bf16x8 pack_bf8(float4 lo, float4 hi) {
    bf16x8 r;
    r[0] = (short)f2bf(lo.x); r[1] = (short)f2bf(lo.y);
    r[2] = (short)f2bf(lo.z); r[3] = (short)f2bf(lo.w);
    r[4] = (short)f2bf(hi.x); r[5] = (short)f2bf(hi.y);
    r[6] = (short)f2bf(hi.z); r[7] = (short)f2bf(hi.w);
    return r;
}

// ---------------- K1: tfeat[b][m] = tanh(mean_t(tXin[b,0,t,:]) @ tproj_w + tproj_b)
__global__ void k_tfeat(const float* __restrict__ tXin, const float* __restrict__ tproj_w,
                        const float* __restrict__ tproj_b, float* __restrict__ tfeat) {
    int b = blockIdx.x;
    int d = threadIdx.x;  // 64 threads
    __shared__ float mv[DD];
    float a = 0.f;
    for (int t = 0; t < TT; ++t)
        a += tXin[((size_t)(b * NN + 0) * TT + t) * DD + d];
    mv[d] = a * (1.f / (float)TT);
    __syncthreads();
    if (d < MM) {
        float acc = tproj_b[d];
        for (int j = 0; j < DD; ++j) acc += mv[j] * tproj_w[j * MM + d];
        tfeat[b * MM + d] = tanhf(acc);
    }
}

// ---------------- K2: support = einsum('btnm,bmtd->bntd'); gcn_out = relu(support@gcn_w + b)
#define TN 64
__global__ __launch_bounds__(256) void k_gcn(const float* __restrict__ matrix,
                                             const float* __restrict__ hidden,
                                             const float* __restrict__ gcn_w,
                                             const float* __restrict__ gcn_b,
                                             float* __restrict__ gcn_out) {
    int bt = blockIdx.x;
    int tile = blockIdx.y;
    int b = bt / TT, t = bt % TT;
    int n0 = tile * TN;

    __shared__ float s_mat[TN][68];
    __shared__ float s_H[64][DD];
    __shared__ float s_gw[DD][DD];

    int tid = threadIdx.x;
    for (int idx = tid; idx < DD * DD; idx += 256)
        s_gw[idx / DD][idx % DD] = gcn_w[idx];

    int r  = tid >> 3;
    int d0 = (tid & 7) << 3;
    float acc0[8], acc1[8];
#pragma unroll
    for (int i = 0; i < 8; ++i) { acc0[i] = 0.f; acc1[i] = 0.f; }

    for (int m0 = 0; m0 < NN; m0 += 64) {
        __syncthreads();
        for (int idx = tid; idx < TN * 64; idx += 256) {
            int rr = idx >> 6, cc = idx & 63;
            int n = n0 + rr, m = m0 + cc;
            s_mat[rr][cc] = (n < NN && m < NN) ? matrix[((size_t)(b * TT + t) * NN + n) * NN + m] : 0.f;
        }
        for (int idx = tid; idx < 64 * DD; idx += 256) {
            int mm = idx >> 6, d = idx & 63;
            int m = m0 + mm;
            s_H[mm][d] = (m < NN) ? hidden[((size_t)(b * NN + m) * TT + t) * DD + d] : 0.f;
        }
        __syncthreads();
        int mmax = (NN - m0 < 64) ? (NN - m0) : 64;
        for (int mm = 0; mm < mmax; ++mm) {
            float w0 = s_mat[r][mm];
            float w1 = s_mat[r + 32][mm];
            float4 h0 = *(const float4*)&s_H[mm][d0];
            float4 h1 = *(const float4*)&s_H[mm][d0 + 4];
            acc0[0] += w0 * h0.x; acc0[1] += w0 * h0.y; acc0[2] += w0 * h0.z; acc0[3] += w0 * h0.w;
            acc0[4] += w0 * h1.x; acc0[5] += w0 * h1.y; acc0[6] += w0 * h1.z; acc0[7] += w0 * h1.w;
            acc1[0] += w1 * h0.x; acc1[1] += w1 * h0.y; acc1[2] += w1 * h0.z; acc1[3] += w1 * h0.w;
            acc1[4] += w1 * h1.x; acc1[5] += w1 * h1.y; acc1[6] += w1 * h1.z; acc1[7] += w1 * h1.w;
        }
    }

    __syncthreads();
    *(float4*)&s_H[r][d0]          = make_float4(acc0[0], acc0[1], acc0[2], acc0[3]);
    *(float4*)&s_H[r][d0 + 4]      = make_float4(acc0[4], acc0[5], acc0[6], acc0[7]);
    *(float4*)&s_H[r + 32][d0]     = make_float4(acc1[0], acc1[1], acc1[2], acc1[3]);
    *(float4*)&s_H[r + 32][d0 + 4] = make_float4(acc1[4], acc1[5], acc1[6], acc1[7]);
    __syncthreads();

    float g0[8], g1[8];
#pragma unroll
    for (int i = 0; i < 8; ++i) { g0[i] = gcn_b[d0 + i]; g1[i] = g0[i]; }
    for (int d = 0; d < DD; ++d) {
        float s0 = s_H[r][d], s1 = s_H[r + 32][d];
        float4 w0 = *(const float4*)&s_gw[d][d0];
        float4 w1 = *(const float4*)&s_gw[d][d0 + 4];
        g0[0] += s0 * w0.x; g0[1] += s0 * w0.y; g0[2] += s0 * w0.z; g0[3] += s0 * w0.w;
        g0[4] += s0 * w1.x; g0[5] += s0 * w1.y; g0[6] += s0 * w1.z; g0[7] += s0 * w1.w;
        g1[0] += s1 * w0.x; g1[1] += s1 * w0.y; g1[2] += s1 * w0.z; g1[3] += s1 * w0.w;
        g1[4] += s1 * w1.x; g1[5] += s1 * w1.y; g1[6] += s1 * w1.z; g1[7] += s1 * w1.w;
    }
#pragma unroll
    for (int i = 0; i < 8; ++i) {
        g0[i] = g0[i] > 0.f ? g0[i] : 0.f;
        g1[i] = g1[i] > 0.f ? g1[i] : 0.f;
    }
    if (n0 + r < NN) {
        size_t base = ((size_t)(b * NN + (n0 + r)) * TT + t) * DD;
        *(float4*)&gcn_out[base + d0]     = make_float4(g0[0], g0[1], g0[2], g0[3]);
        *(float4*)&gcn_out[base + d0 + 4] = make_float4(g0[4], g0[5], g0[6], g0[7]);
    }
    if (n0 + r + 32 < NN) {
        size_t base = ((size_t)(b * NN + (n0 + r + 32)) * TT + t) * DD;
        *(float4*)&gcn_out[base + d0]     = make_float4(g1[0], g1[1], g1[2], g1[3]);
        *(float4*)&gcn_out[base + d0 + 4] = make_float4(g1[4], g1[5], g1[6], g1[7]);
    }
}

// ---------------- K3a: Wp = sum_m e[m]*W[m], stored bf16 in MFMA B-fragment-major layout:
// per (node, p): u16[nt(8)][ks(4)][lane(64)][j(8)]; element (i,k) -> nt=k>>4, ks=i>>5,
// lane=(k&15)|(((i>>3)&3)<<4), j=i&7.  grid (ceil(Uc/16), 48); block 256.
__global__ __launch_bounds__(256) void k_wp(
    const float* __restrict__ node_emb, const float* __restrict__ tfeat,
    const float* __restrict__ WQ, const float* __restrict__ WK, const float* __restrict__ WV,
    unsigned short* __restrict__ wp, int u0, int Uc) {
    int un0 = blockIdx.x * 16;
    int chunk = blockIdx.y;                 // 0..47
    int p = chunk >> 4;                     // 0=Q 1=K 2=V
    int off = (chunk & 15) << 10;           // 1024-elem chunk within 16384
    int tid = threadIdx.x;
    const float* __restrict__ W = (p == 0) ? WQ : ((p == 1) ? WK : WV);

    __shared__ float s_e[16][MM];
    {
        int nn = tid >> 4, m = tid & 15;    // 256 = 16*16 exactly
        int us = un0 + nn;
        float e = 0.f;
        if (us < Uc) {
            int u = u0 + us;
            int b = u / NN, n = u % NN;
            e = node_emb[n * MM + m] * tfeat[b * MM + m];
        }
        s_e[nn][m] = e;
    }
    __syncthreads();

    int j = off + tid * 4;                  // flat [i][k], k contiguous
    int i  = j >> 7;                        // input-dim row 0..127
    int k0 = j & 127;                       // output col, 4-aligned
    float4 acc[16];
#pragma unroll
    for (int nn = 0; nn < 16; ++nn) acc[nn] = make_float4(0.f, 0.f, 0.f, 0.f);
#pragma unroll
    for (int m = 0; m < MM; ++m) {
        float4 w = *(const float4*)&W[(size_t)m * 16384 + j];
#pragma unroll
        for (int nn = 0; nn < 16; ++nn) {
            float e = s_e[nn][m];
            acc[nn].x += e * w.x; acc[nn].y += e * w.y;
            acc[nn].z += e * w.z; acc[nn].w += e * w.w;
        }
    }

    // fragment store offsets (same for all 16 nodes)
    int ks = i >> 5;
    int jf = i & 7;
    int lhi = ((i >> 3) & 3) << 4;
    int nt = k0 >> 4;                       // k0..k0+3 share nt (k0 4-aligned)
    int fbase = p * 16384 + ((nt * 4 + ks) * 64) * 8 + jf;
    int foff[4];
#pragma unroll
    for (int c = 0; c < 4; ++c)
        foff[c] = fbase + ((((k0 + c) & 15) | lhi) << 3);

#pragma unroll
    for (int nn = 0; nn < 16; ++nn) {
        int us = un0 + nn;
        if (us < Uc) {
            unsigned short* dst = wp + (size_t)us * 49152;
            dst[foff[0]] = f2bf(acc[nn].x);
            dst[foff[1]] = f2bf(acc[nn].y);
            dst[foff[2]] = f2bf(acc[nn].z);
            dst[foff[3]] = f2bf(acc[nn].w);
        }
    }
}

// ---------------- K3b: per node MFMA proj -> lrelu -> qkv bf16 to workspace.
// 256 threads (4 waves); wave w owns n-tiles {w, w+4}. Pure-GEMM register profile (~90 regs).
__global__ __launch_bounds__(256) void k_proj(
    const float* __restrict__ hidden, const float* __restrict__ tXin,
    const unsigned short* __restrict__ wp, unsigned short* __restrict__ qkv,
    int u0) {
    int us = blockIdx.x;
    int u = u0 + us;
    int tid = threadIdx.x;
    int lane = tid & 63, wid = tid >> 6;
    int trow = lane & 15, kgrp = lane >> 4;

    size_t base = (size_t)u * TT * DD;

    // A fragments: x = [hidden | tXin] rows, bf16. A[t][i]: t=lane&15 (+16), i=ks*32+(lane>>4)*8+j
    bf16x8 afrag[2][4];
#pragma unroll
    for (int mt = 0; mt < 2; ++mt) {
        int t = mt * 16 + trow;
        bool valid = (t < TT);
#pragma unroll
        for (int ks = 0; ks < 4; ++ks) {
            int i0 = ks * 32 + kgrp * 8;
            float4 lo = make_float4(0.f, 0.f, 0.f, 0.f), hi = lo;
            if (valid) {
                const float* src = (i0 < DD) ? &hidden[base + t * DD + i0]
                                             : &tXin[base + t * DD + (i0 - DD)];
                lo = *(const float4*)src;
                hi = *(const float4*)(src + 4);
            }
            afrag[mt][ks] = pack_bf8(lo, hi);
        }
    }

    const unsigned short* wbase = wp + (size_t)us * 49152;
    unsigned short* qbase = qkv + (size_t)us * (3 * TT * E2);
    int rowg = kgrp * 4;
    int col0 = wid * 16 + trow;
    int col1 = (wid + 4) * 16 + trow;
#pragma unroll 1
    for (int p = 0; p < 3; ++p) {
        f32x4 acc00 = {0.f, 0.f, 0.f, 0.f}, acc01 = acc00, acc10 = acc00, acc11 = acc00;
#pragma unroll
        for (int ks = 0; ks < 4; ++ks) {
            union { uint4 u4; bf16x8 v; } c0, c1;
            c0.u4 = *(const uint4*)(wbase + (size_t)p * 16384 + (((wid) * 4 + ks) * 64 + lane) * 8);
            c1.u4 = *(const uint4*)(wbase + (size_t)p * 16384 + (((wid + 4) * 4 + ks) * 64 + lane) * 8);
            acc00 = __builtin_amdgcn_mfma_f32_16x16x32_bf16(afrag[0][ks], c0.v, acc00, 0, 0, 0);
            acc10 = __builtin_amdgcn_mfma_f32_16x16x32_bf16(afrag[1][ks], c0.v, acc10, 0, 0, 0);
            acc01 = __builtin_amdgcn_mfma_f32_16x16x32_bf16(afrag[0][ks], c1.v, acc01, 0, 0, 0);
            acc11 = __builtin_amdgcn_mfma_f32_16x16x32_bf16(afrag[1][ks], c1.v, acc11, 0, 0, 0);
        }
        // C layout: row=(lane>>4)*4+r (+16 for mt1), col = nt*16+(lane&15); lrelu; store u16
#pragma unroll
        for (int r = 0; r < 4; ++r) {
            int t = rowg + r;
            float v0 = acc00[r]; v0 = (v0 >= 0.f) ? v0 : NEG * v0;
            float v1 = acc01[r]; v1 = (v1 >= 0.f) ? v1 : NEG * v1;
            qbase[(p * TT + t) * E2 + col0] = f2bf(v0);
            qbase[(p * TT + t) * E2 + col1] = f2bf(v1);
        }
        if (rowg < 8) {
#pragma unroll
            for (int r = 0; r < 4; ++r) {
                int t = 16 + rowg + r;
                float v0 = acc10[r]; v0 = (v0 >= 0.f) ? v0 : NEG * v0;
                float v1 = acc11[r]; v1 = (v1 >= 0.f) ? v1 : NEG * v1;
                qbase[(p * TT + t) * E2 + col0] = f2bf(v0);
                qbase[(p * TT + t) * E2 + col1] = f2bf(v1);
            }
        }
    }
}

// ---------------- K3c: per node: attention + out-proj + gate + residual (R6-verified phases)
// arena u32[8832]: qkv u32[3][24][66] @0 | sc u32[8][24][13] @4752 | val u32[24][66] @7248
#define QKS 66
#define QKP (TT * QKS)          // 1584 u32 per proj plane
#define SC_OFF 4752
#define VAL_OFF 7248
__global__ __launch_bounds__(256) void k_attn2(
    const unsigned* __restrict__ qkv, const float* __restrict__ hidden,
    const float* __restrict__ out_w, const float* __restrict__ out_b,
    const float* __restrict__ gate_w, const float* __restrict__ gate_b,
    const float* __restrict__ gcn_out, float* __restrict__ out,
    int u0) {
    int us = blockIdx.x;
    int u = u0 + us;
    int tid = threadIdx.x;

    __shared__ __align__(16) unsigned arena[8832];
    __shared__ float s_gcn[TT][68];
    __shared__ float s_value[TT][68];

    size_t base = (size_t)u * TT * DD;

    // load packed qkv (u32 k-pairs) into arena + gcn staging
    const unsigned* src = qkv + (size_t)us * (3 * TT * 64);
    for (int idx = tid; idx < 3 * TT * 64; idx += 256) {
        int p = idx / (TT * 64);
        int r = idx % (TT * 64);
        int t = r >> 6, kp = r & 63;
        arena[p * QKP + t * QKS + kp] = src[idx];
    }
    for (int idx = tid; idx < TT * DD; idx += 256)
        s_gcn[idx >> 6][idx & 63] = gcn_out[base + idx];
    unsigned* s_qkv = arena;
    __syncthreads();

    // ---- phase C1: scores w[h][t][s] = exp(scale * q.k) for s<=t, 0 otherwise (packed pairs)
    unsigned* s_sc = arena + SC_OFF;
    if (tid < HH * TT) {
        int h = tid / TT, t = tid % TT;
        const float scale = 0.25f;
        float qf[16];
#pragma unroll
        for (int j = 0; j < 8; ++j) {
            unsigned uq = s_qkv[0 * QKP + t * QKS + 8 * h + j];
            qf[2 * j] = bflo(uq); qf[2 * j + 1] = bfhi(uq);
        }
#pragma unroll
        for (int s2 = 0; s2 < 12; ++s2) {
            int s0 = 2 * s2;
            float d0 = 0.f, d1 = 0.f;
#pragma unroll
            for (int j = 0; j < 8; ++j) {
                unsigned ka = s_qkv[1 * QKP + s0 * QKS + 8 * h + j];
                unsigned kb = s_qkv[1 * QKP + (s0 + 1) * QKS + 8 * h + j];
                d0 += qf[2 * j] * bflo(ka) + qf[2 * j + 1] * bfhi(ka);
                d1 += qf[2 * j] * bflo(kb) + qf[2 * j + 1] * bfhi(kb);
            }
            float w0 = (s0 <= t) ? __expf(d0 * scale) : 0.f;
            float w1 = (s0 + 1 <= t) ? __expf(d1 * scale) : 0.f;
            s_sc[(h * TT + t) * 13 + s2] = packbf(w0, w1);
        }
    }
    __syncthreads();

    // ---- phase C2: normalize + PV -> packed val[24][66]
    unsigned* s_val = arena + VAL_OFF;
#pragma unroll
    for (int it = 0; it < 3; ++it) {
        int item = tid + it * 256;             // < 768
        int h = item / 96;
        int r = item % 96;
        int t = r >> 2, d4 = r & 3;
        int kg0 = 8 * h + 2 * d4;
        float sum = 0.f, v0 = 0.f, v1 = 0.f, v2 = 0.f, v3 = 0.f;
#pragma unroll
        for (int s2 = 0; s2 < 12; ++s2) {
            unsigned uw = s_sc[(h * TT + t) * 13 + s2];
            float w0 = bflo(uw), w1 = bfhi(uw);
            sum += w0 + w1;
            unsigned ua = s_qkv[2 * QKP + (2 * s2) * QKS + kg0];
            unsigned ub = s_qkv[2 * QKP + (2 * s2) * QKS + kg0 + 1];
            v0 += w0 * bflo(ua); v1 += w0 * bfhi(ua);
            v2 += w0 * bflo(ub); v3 += w0 * bfhi(ub);
            unsigned uc = s_qkv[2 * QKP + (2 * s2 + 1) * QKS + kg0];
            unsigned ud = s_qkv[2 * QKP + (2 * s2 + 1) * QKS + kg0 + 1];
            v0 += w1 * bflo(uc); v1 += w1 * bfhi(uc);
            v2 += w1 * bflo(ud); v3 += w1 * bfhi(ud);
        }
        float inv = 1.f / sum;
        s_val[t * QKS + kg0]     = packbf(v0 * inv, v1 * inv);
        s_val[t * QKS + kg0 + 1] = packbf(v2 * inv, v3 * inv);
    }
    __syncthreads();

    // ---- phase D: value = lrelu(val @ out_w + out_b)
    for (int o = tid; o < TT * 16; o += 256) {
        int tq = o >> 4;
        int dd0 = (o & 15) * 4;
        float4 a = *(const float4*)&out_b[dd0];
        for (int j0 = 0; j0 < E2; j0 += 4) {
            unsigned xa = s_val[tq * QKS + j0 / 2];
            unsigned xb = s_val[tq * QKS + j0 / 2 + 1];
            float x0 = bflo(xa), x1 = bfhi(xa), x2 = bflo(xb), x3 = bfhi(xb);
            const float4 w0 = *(const float4*)&out_w[(j0 + 0) * DD + dd0];
            const float4 w1 = *(const float4*)&out_w[(j0 + 1) * DD + dd0];
            const float4 w2 = *(const float4*)&out_w[(j0 + 2) * DD + dd0];
            const float4 w3 = *(const float4*)&out_w[(j0 + 3) * DD + dd0];
            a.x += x0 * w0.x + x1 * w1.x + x2 * w2.x + x3 * w3.x;
            a.y += x0 * w0.y + x1 * w1.y + x2 * w2.y + x3 * w3.y;
            a.z += x0 * w0.z + x1 * w1.z + x2 * w2.z + x3 * w3.z;
            a.w += x0 * w0.w + x1 * w1.w + x2 * w2.w + x3 * w3.w;
        }
        a.x = (a.x >= 0.f) ? a.x : NEG * a.x;
        a.y = (a.y >= 0.f) ? a.y : NEG * a.y;
        a.z = (a.z >= 0.f) ? a.z : NEG * a.z;
        a.w = (a.w >= 0.f) ? a.w : NEG * a.w;
        *(float4*)&s_value[tq][dd0] = a;
    }
    __syncthreads();

    // ---- phase E: gate + residual
    for (int o = tid; o < TT * 16; o += 256) {
        int tq = o >> 4;
        int dd0 = (o & 15) * 4;
        float4 zz = *(const float4*)&gate_b[dd0];
        for (int j0 = 0; j0 < DD; j0 += 4) {
            const float4 x = *(const float4*)&s_gcn[tq][j0];
            const float4 w0 = *(const float4*)&gate_w[(j0 + 0) * DD + dd0];
            const float4 w1 = *(const float4*)&gate_w[(j0 + 1) * DD + dd0];
            const float4 w2 = *(const float4*)&gate_w[(j0 + 2) * DD + dd0];
            const float4 w3 = *(const float4*)&gate_w[(j0 + 3) * DD + dd0];
            zz.x += x.x * w0.x + x.y * w1.x + x.z * w2.x + x.w * w3.x;
            zz.y += x.x * w0.y + x.y * w1.y + x.z * w2.y + x.w * w3.y;
            zz.z += x.x * w0.z + x.y * w1.z + x.z * w2.z + x.w * w3.z;
            zz.w += x.x * w0.w + x.y * w1.w + x.z * w2.w + x.w * w3.w;
        }
        for (int j0 = 0; j0 < DD; j0 += 4) {
            const float4 x = *(const float4*)&s_value[tq][j0];
            const float4 w0 = *(const float4*)&gate_w[(DD + j0 + 0) * DD + dd0];
            const float4 w1 = *(const float4*)&gate_w[(DD + j0 + 1) * DD + dd0];
            const float4 w2 = *(const float4*)&gate_w[(DD + j0 + 2) * DD + dd0];
            const float4 w3 = *(const float4*)&gate_w[(DD + j0 + 3) * DD + dd0];
            zz.x += x.x * w0.x + x.y * w1.x + x.z * w2.x + x.w * w3.x;
            zz.y += x.x * w0.y + x.y * w1.y + x.z * w2.y + x.w * w3.y;
            zz.z += x.x * w0.z + x.y * w1.z + x.z * w2.z + x.w * w3.z;
            zz.w += x.x * w0.w + x.y * w1.w + x.z * w2.w + x.w * w3.w;
        }
        size_t ob = base + tq * DD + dd0;
        const float4 hv = *(const float4*)&hidden[ob];
        const float4 gv = *(const float4*)&s_gcn[tq][dd0];
        const float4 vv = *(const float4*)&s_value[tq][dd0];
        float4 oo;
        float z;
        z = 1.f / (1.f + __expf(-zz.x)); oo.x = z * gv.x + (1.f - z) * vv.x + hv.x;
        z = 1.f / (1.f + __expf(-zz.y)); oo.y = z * gv.y + (1.f - z) * vv.y + hv.y;
        z = 1.f / (1.f + __expf(-zz.z)); oo.z = z * gv.z + (1.f - z) * vv.z + hv.z;
        z = 1.f / (1.f + __expf(-zz.w)); oo.w = z * gv.w + (1.f - z) * vv.w + hv.w;
        *(float4*)&out[ob] = oo;
    }
}

extern "C" void kernel_launch(void* const* d_in, const int* in_sizes, int n_in,
                              void* d_out, int out_size, void* d_ws, size_t ws_size,
                              hipStream_t stream) {
    const float* hidden   = (const float*)d_in[0];
    const float* tXin     = (const float*)d_in[1];
    const float* matrix   = (const float*)d_in[2];
    const float* gcn_w    = (const float*)d_in[3];
    const float* gcn_b    = (const float*)d_in[4];
    const float* node_emb = (const float*)d_in[5];
    const float* tproj_w  = (const float*)d_in[6];
    const float* tproj_b  = (const float*)d_in[7];
    const float* WK_      = (const float*)d_in[8];   // dict order: WK, WQ, WV
    const float* WQ_      = (const float*)d_in[9];
    const float* WV_      = (const float*)d_in[10];
    const float* out_w    = (const float*)d_in[11];
    const float* out_b    = (const float*)d_in[12];
    const float* gate_w   = (const float*)d_in[13];
    const float* gate_b   = (const float*)d_in[14];
    float* out = (float*)d_out;

    char* ws = (char*)d_ws;
    float* tfeat   = (float*)ws;                         // 512 B
    float* gcn_out = (float*)(ws + 512);                 // 15,974,400 B
    size_t off_wp  = 512 + (size_t)BB * NN * TT * DD * 4;

    const size_t per_wp  = 3 * (size_t)E2 * E2 * 2;      // 98304 B per node (bf16)
    const size_t per_qkv = 3 * (size_t)TT * E2 * 2;      // 18432 B per node (bf16)
    long long avail = (long long)ws_size - (long long)off_wp;
    long long Ull = avail / (long long)(per_wp + per_qkv);
    int U = (Ull < 1) ? 1 : ((Ull > NNODE) ? NNODE : (int)Ull);

    unsigned short* wp_buf  = (unsigned short*)(ws + off_wp);
    unsigned short* qkv_buf = (unsigned short*)(ws + off_wp + (size_t)U * per_wp);

    k_tfeat<<<BB, DD, 0, stream>>>(tXin, tproj_w, tproj_b, tfeat);
    k_gcn<<<dim3(BB * TT, (NN + TN - 1) / TN), 256, 0, stream>>>(matrix, hidden, gcn_w, gcn_b, gcn_out);

    for (int u0 = 0; u0 < NNODE; u0 += U) {
        int Uc = (NNODE - u0 < U) ? (NNODE - u0) : U;
        k_wp<<<dim3((Uc + 15) / 16, 48), 256, 0, stream>>>(node_emb, tfeat, WQ_, WK_, WV_,
                                                           wp_buf, u0, Uc);
        k_proj<<<Uc, 256, 0, stream>>>(hidden, tXin, wp_buf, qkv_buf, u0);
        k_attn2<<<Uc, 256, 0, stream>>>((const unsigned*)qkv_buf, hidden, out_w, out_b,
                                        gate_w, gate_b, gcn_out, out, u0);
    }
}

// Round 10
// 579.790 us; speedup vs baseline: 2.5516x; 1.2270x over previous
//
#include <hip/hip_runtime.h>
#include <math.h>

#define BB 8
#define NN 325
#define TT 24
#define DD 64
#define HH 8
#define MM 16
#define E2 128
#define DK 16
#define NEG 0.1f
#define NNODE (BB * NN)          // 2600

typedef short bf16x8 __attribute__((ext_vector_type(8)));
typedef float f32x4 __attribute__((ext_vector_type(4)));

__device__ __forceinline__ unsigned short f2bf(float f) {
    union { float f; unsigned u; } v; v.f = f;
    unsigned r = v.u + 0x7fffu + ((v.u >> 16) & 1u);   // RNE
    return (unsigned short)(r >> 16);
}
__device__ __forceinline__ unsigned packbf(float a, float b) {
    return (unsigned)f2bf(a) | ((unsigned)f2bf(b) << 16);
}
__device__ __forceinline__ float bflo(unsigned u) { return __uint_as_float(u << 16); }
__device__ __forceinline__ float bfhi(unsigned u) { return __uint_as_float(u & 0xffff0000u); }

__device__ __forceinline__ bf16x8 pack_bf8(float4 lo, float4 hi) {
    bf16x8 r;
    r[0] = (short)f2bf(lo.x); r[1] = (short)f2bf(lo.y);
    r[2] = (short)f2bf(lo.z); r[3] = (short)f2bf(lo.w);
    r[4] = (short)f2bf(hi.x); r[5] = (short)f2bf(hi.y);
    r[6] = (short)f2bf(hi.z); r[7] = (short)f2bf(hi.w);
    return r;
}

// ---------------- K1: tfeat[b][m] = tanh(mean_t(tXin[b,0,t,:]) @ tproj_w + tproj_b)
__global__ void k_tfeat(const float* __restrict__ tXin, const float* __restrict__ tproj_w,
                        const float* __restrict__ tproj_b, float* __restrict__ tfeat) {
    int b = blockIdx.x;
    int d = threadIdx.x;  // 64 threads
    __shared__ float mv[DD];
    float a = 0.f;
    for (int t = 0; t < TT; ++t)
        a += tXin[((size_t)(b * NN + 0) * TT + t) * DD + d];
    mv[d] = a * (1.f / (float)TT);
    __syncthreads();
    if (d < MM) {
        float acc = tproj_b[d];
        for (int j = 0; j < DD; ++j) acc += mv[j] * tproj_w[j * MM + d];
        tfeat[b * MM + d] = tanhf(acc);
    }
}

// ---------------- K2: support = einsum('btnm,bmtd->bntd'); gcn_out = relu(support@gcn_w + b)
#define TN 64
__global__ __launch_bounds__(256) void k_gcn(const float* __restrict__ matrix,
                                             const float* __restrict__ hidden,
                                             const float* __restrict__ gcn_w,
                                             const float* __restrict__ gcn_b,
                                             float* __restrict__ gcn_out) {
    int bt = blockIdx.x;
    int tile = blockIdx.y;
    int b = bt / TT, t = bt % TT;
    int n0 = tile * TN;

    __shared__ float s_mat[TN][68];
    __shared__ float s_H[64][DD];
    __shared__ float s_gw[DD][DD];

    int tid = threadIdx.x;
    for (int idx = tid; idx < DD * DD; idx += 256)
        s_gw[idx / DD][idx % DD] = gcn_w[idx];

    int r  = tid >> 3;
    int d0 = (tid & 7) << 3;
    float acc0[8], acc1[8];
#pragma unroll
    for (int i = 0; i < 8; ++i) { acc0[i] = 0.f; acc1[i] = 0.f; }

    for (int m0 = 0; m0 < NN; m0 += 64) {
        __syncthreads();
        for (int idx = tid; idx < TN * 64; idx += 256) {
            int rr = idx >> 6, cc = idx & 63;
            int n = n0 + rr, m = m0 + cc;
            s_mat[rr][cc] = (n < NN && m < NN) ? matrix[((size_t)(b * TT + t) * NN + n) * NN + m] : 0.f;
        }
        for (int idx = tid; idx < 64 * DD; idx += 256) {
            int mm = idx >> 6, d = idx & 63;
            int m = m0 + mm;
            s_H[mm][d] = (m < NN) ? hidden[((size_t)(b * NN + m) * TT + t) * DD + d] : 0.f;
        }
        __syncthreads();
        int mmax = (NN - m0 < 64) ? (NN - m0) : 64;
        for (int mm = 0; mm < mmax; ++mm) {
            float w0 = s_mat[r][mm];
            float w1 = s_mat[r + 32][mm];
            float4 h0 = *(const float4*)&s_H[mm][d0];
            float4 h1 = *(const float4*)&s_H[mm][d0 + 4];
            acc0[0] += w0 * h0.x; acc0[1] += w0 * h0.y; acc0[2] += w0 * h0.z; acc0[3] += w0 * h0.w;
            acc0[4] += w0 * h1.x; acc0[5] += w0 * h1.y; acc0[6] += w0 * h1.z; acc0[7] += w0 * h1.w;
            acc1[0] += w1 * h0.x; acc1[1] += w1 * h0.y; acc1[2] += w1 * h0.z; acc1[3] += w1 * h0.w;
            acc1[4] += w1 * h1.x; acc1[5] += w1 * h1.y; acc1[6] += w1 * h1.z; acc1[7] += w1 * h1.w;
        }
    }

    __syncthreads();
    *(float4*)&s_H[r][d0]          = make_float4(acc0[0], acc0[1], acc0[2], acc0[3]);
    *(float4*)&s_H[r][d0 + 4]      = make_float4(acc0[4], acc0[5], acc0[6], acc0[7]);
    *(float4*)&s_H[r + 32][d0]     = make_float4(acc1[0], acc1[1], acc1[2], acc1[3]);
    *(float4*)&s_H[r + 32][d0 + 4] = make_float4(acc1[4], acc1[5], acc1[6], acc1[7]);
    __syncthreads();

    float g0[8], g1[8];
#pragma unroll
    for (int i = 0; i < 8; ++i) { g0[i] = gcn_b[d0 + i]; g1[i] = g0[i]; }
    for (int d = 0; d < DD; ++d) {
        float s0 = s_H[r][d], s1 = s_H[r + 32][d];
        float4 w0 = *(const float4*)&s_gw[d][d0];
        float4 w1 = *(const float4*)&s_gw[d][d0 + 4];
        g0[0] += s0 * w0.x; g0[1] += s0 * w0.y; g0[2] += s0 * w0.z; g0[3] += s0 * w0.w;
        g0[4] += s0 * w1.x; g0[5] += s0 * w1.y; g0[6] += s0 * w1.z; g0[7] += s0 * w1.w;
        g1[0] += s1 * w0.x; g1[1] += s1 * w0.y; g1[2] += s1 * w0.z; g1[3] += s1 * w0.w;
        g1[4] += s1 * w1.x; g1[5] += s1 * w1.y; g1[6] += s1 * w1.z; g1[7] += s1 * w1.w;
    }
#pragma unroll
    for (int i = 0; i < 8; ++i) {
        g0[i] = g0[i] > 0.f ? g0[i] : 0.f;
        g1[i] = g1[i] > 0.f ? g1[i] : 0.f;
    }
    if (n0 + r < NN) {
        size_t base = ((size_t)(b * NN + (n0 + r)) * TT + t) * DD;
        *(float4*)&gcn_out[base + d0]     = make_float4(g0[0], g0[1], g0[2], g0[3]);
        *(float4*)&gcn_out[base + d0 + 4] = make_float4(g0[4], g0[5], g0[6], g0[7]);
    }
    if (n0 + r + 32 < NN) {
        size_t base = ((size_t)(b * NN + (n0 + r + 32)) * TT + t) * DD;
        *(float4*)&gcn_out[base + d0]     = make_float4(g1[0], g1[1], g1[2], g1[3]);
        *(float4*)&gcn_out[base + d0 + 4] = make_float4(g1[4], g1[5], g1[6], g1[7]);
    }
}

// ---------------- K3a: Wp = sum_m e[m]*W[m], bf16 in MFMA B-fragment-major layout.
// Fragment u16 index: p*16384 + (nt*4+ks)*512 + (k&15)*8 + L*128 + jf,
//   nt=k>>4, ks=i>>5, L=(i>>3)&3, jf=i&7.
// Block = (16 nodes, chunk): chunk -> p = chunk>>4, c = chunk&15 -> i in [c*8, c*8+8), all k.
// ks=c>>2 and L=c&3 are UNIFORM per block -> chunk output = 8 nt-groups x 128 contiguous u16.
// Compute keeps coalesced float4 W reads; results staged in LDS (cheap u16 scatter),
// then written out as fully-coalesced uint4 stores (fixes R9's 2-byte global scatter).
__global__ __launch_bounds__(256) void k_wp(
    const float* __restrict__ node_emb, const float* __restrict__ tfeat,
    const float* __restrict__ WQ, const float* __restrict__ WK, const float* __restrict__ WV,
    unsigned short* __restrict__ wp, int u0, int Uc) {
    int un0 = blockIdx.x * 16;
    int chunk = blockIdx.y;                 // 0..47
    int p = chunk >> 4;                     // 0=Q 1=K 2=V
    int c = chunk & 15;                     // i-block
    int off = c << 10;                      // 1024-elem chunk within 16384
    int tid = threadIdx.x;
    const float* __restrict__ W = (p == 0) ? WQ : ((p == 1) ? WK : WV);

    __shared__ float s_e[16][MM];
    __shared__ __align__(16) unsigned short s_out[16][1024];   // 32 KB

    {
        int nn = tid >> 4, m = tid & 15;    // 256 = 16*16 exactly
        int us = un0 + nn;
        float e = 0.f;
        if (us < Uc) {
            int u = u0 + us;
            int b = u / NN, n = u % NN;
            e = node_emb[n * MM + m] * tfeat[b * MM + m];
        }
        s_e[nn][m] = e;
    }
    __syncthreads();

    int j = off + tid * 4;                  // flat [i][k], k contiguous
    int k0 = j & 127;                       // output col, 4-aligned
    float4 acc[16];
#pragma unroll
    for (int nn = 0; nn < 16; ++nn) acc[nn] = make_float4(0.f, 0.f, 0.f, 0.f);
#pragma unroll
    for (int m = 0; m < MM; ++m) {
        float4 w = *(const float4*)&W[(size_t)m * 16384 + j];
#pragma unroll
        for (int nn = 0; nn < 16; ++nn) {
            float e = s_e[nn][m];
            acc[nn].x += e * w.x; acc[nn].y += e * w.y;
            acc[nn].z += e * w.z; acc[nn].w += e * w.w;
        }
    }

    // scatter bf16 into LDS (chunk-local fragment order: nt*128 + (k&15)*8 + jf)
    int nt = k0 >> 4;
    int jf = tid >> 5;                      // = i & 7
    int lb = nt * 128 + jf;
    int s0 = (k0 & 15) * 8;                 // k0 4-aligned: k15+cc stays in [0,15]
#pragma unroll
    for (int nn = 0; nn < 16; ++nn) {
        s_out[nn][lb + s0]      = f2bf(acc[nn].x);
        s_out[nn][lb + s0 + 8]  = f2bf(acc[nn].y);
        s_out[nn][lb + s0 + 16] = f2bf(acc[nn].z);
        s_out[nn][lb + s0 + 24] = f2bf(acc[nn].w);
    }
    __syncthreads();

    // coalesced writeout: 2048 uint4 total, 8 per thread
    int ks = c >> 2, L = c & 3;
    size_t gbase = (size_t)p * 16384 + (size_t)ks * 512 + (size_t)L * 128;
#pragma unroll
    for (int ii = 0; ii < 8; ++ii) {
        int o = ii * 256 + tid;
        int node = o >> 7, r = o & 127;
        int ntw = r >> 4, w = r & 15;
        int us = un0 + node;
        if (us < Uc) {
            uint4 v = *(const uint4*)&s_out[node][ntw * 128 + w * 8];
            *(uint4*)&wp[(size_t)us * 49152 + gbase + (size_t)ntw * 2048 + w * 8] = v;
        }
    }
}

// ---------------- K3b: per node MFMA proj -> lrelu -> qkv bf16 to workspace.
// 256 threads (4 waves); wave w owns n-tiles {w, w+4}. Pure-GEMM register profile (~90 regs).
__global__ __launch_bounds__(256) void k_proj(
    const float* __restrict__ hidden, const float* __restrict__ tXin,
    const unsigned short* __restrict__ wp, unsigned short* __restrict__ qkv,
    int u0) {
    int us = blockIdx.x;
    int u = u0 + us;
    int tid = threadIdx.x;
    int lane = tid & 63, wid = tid >> 6;
    int trow = lane & 15, kgrp = lane >> 4;

    size_t base = (size_t)u * TT * DD;

    // A fragments: x = [hidden | tXin] rows, bf16. A[t][i]: t=lane&15 (+16), i=ks*32+(lane>>4)*8+j
    bf16x8 afrag[2][4];
#pragma unroll
    for (int mt = 0; mt < 2; ++mt) {
        int t = mt * 16 + trow;
        bool valid = (t < TT);
#pragma unroll
        for (int ks = 0; ks < 4; ++ks) {
            int i0 = ks * 32 + kgrp * 8;
            float4 lo = make_float4(0.f, 0.f, 0.f, 0.f), hi = lo;
            if (valid) {
                const float* src = (i0 < DD) ? &hidden[base + t * DD + i0]
                                             : &tXin[base + t * DD + (i0 - DD)];
                lo = *(const float4*)src;
                hi = *(const float4*)(src + 4);
            }
            afrag[mt][ks] = pack_bf8(lo, hi);
        }
    }

    const unsigned short* wbase = wp + (size_t)us * 49152;
    unsigned short* qbase = qkv + (size_t)us * (3 * TT * E2);
    int rowg = kgrp * 4;
    int col0 = wid * 16 + trow;
    int col1 = (wid + 4) * 16 + trow;
#pragma unroll 1
    for (int p = 0; p < 3; ++p) {
        f32x4 acc00 = {0.f, 0.f, 0.f, 0.f}, acc01 = acc00, acc10 = acc00, acc11 = acc00;
#pragma unroll
        for (int ks = 0; ks < 4; ++ks) {
            union { uint4 u4; bf16x8 v; } c0, c1;
            c0.u4 = *(const uint4*)(wbase + (size_t)p * 16384 + (((wid) * 4 + ks) * 64 + lane) * 8);
            c1.u4 = *(const uint4*)(wbase + (size_t)p * 16384 + (((wid + 4) * 4 + ks) * 64 + lane) * 8);
            acc00 = __builtin_amdgcn_mfma_f32_16x16x32_bf16(afrag[0][ks], c0.v, acc00, 0, 0, 0);
            acc10 = __builtin_amdgcn_mfma_f32_16x16x32_bf16(afrag[1][ks], c0.v, acc10, 0, 0, 0);
            acc01 = __builtin_amdgcn_mfma_f32_16x16x32_bf16(afrag[0][ks], c1.v, acc01, 0, 0, 0);
            acc11 = __builtin_amdgcn_mfma_f32_16x16x32_bf16(afrag[1][ks], c1.v, acc11, 0, 0, 0);
        }
        // C layout: row=(lane>>4)*4+r (+16 for mt1), col = nt*16+(lane&15); lrelu; store u16
#pragma unroll
        for (int r = 0; r < 4; ++r) {
            int t = rowg + r;
            float v0 = acc00[r]; v0 = (v0 >= 0.f) ? v0 : NEG * v0;
            float v1 = acc01[r]; v1 = (v1 >= 0.f) ? v1 : NEG * v1;
            qbase[(p * TT + t) * E2 + col0] = f2bf(v0);
            qbase[(p * TT + t) * E2 + col1] = f2bf(v1);
        }
        if (rowg < 8) {
#pragma unroll
            for (int r = 0; r < 4; ++r) {
                int t = 16 + rowg + r;
                float v0 = acc10[r]; v0 = (v0 >= 0.f) ? v0 : NEG * v0;
                float v1 = acc11[r]; v1 = (v1 >= 0.f) ? v1 : NEG * v1;
                qbase[(p * TT + t) * E2 + col0] = f2bf(v0);
                qbase[(p * TT + t) * E2 + col1] = f2bf(v1);
            }
        }
    }
}

// ---------------- K3c: per node: attention + out-proj + gate + residual (R6-verified phases)
// arena u32[8832]: qkv u32[3][24][66] @0 | sc u32[8][24][13] @4752 | val u32[24][66] @7248
#define QKS 66
#define QKP (TT * QKS)          // 1584 u32 per proj plane
#define SC_OFF 4752
#define VAL_OFF 7248
__global__ __launch_bounds__(256) void k_attn2(
    const unsigned* __restrict__ qkv, const float* __restrict__ hidden,
    const float* __restrict__ out_w, const float* __restrict__ out_b,
    const float* __restrict__ gate_w, const float* __restrict__ gate_b,
    const float* __restrict__ gcn_out, float* __restrict__ out,
    int u0) {
    int us = blockIdx.x;
    int u = u0 + us;
    int tid = threadIdx.x;

    __shared__ __align__(16) unsigned arena[8832];
    __shared__ float s_gcn[TT][68];
    __shared__ float s_value[TT][68];

    size_t base = (size_t)u * TT * DD;

    // load packed qkv (u32 k-pairs) into arena + gcn staging
    const unsigned* src = qkv + (size_t)us * (3 * TT * 64);
    for (int idx = tid; idx < 3 * TT * 64; idx += 256) {
        int p = idx / (TT * 64);
        int r = idx % (TT * 64);
        int t = r >> 6, kp = r & 63;
        arena[p * QKP + t * QKS + kp] = src[idx];
    }
    for (int idx = tid; idx < TT * DD; idx += 256)
        s_gcn[idx >> 6][idx & 63] = gcn_out[base + idx];
    unsigned* s_qkv = arena;
    __syncthreads();

    // ---- phase C1: scores w[h][t][s] = exp(scale * q.k) for s<=t, 0 otherwise (packed pairs)
    unsigned* s_sc = arena + SC_OFF;
    if (tid < HH * TT) {
        int h = tid / TT, t = tid % TT;
        const float scale = 0.25f;
        float qf[16];
#pragma unroll
        for (int j = 0; j < 8; ++j) {
            unsigned uq = s_qkv[0 * QKP + t * QKS + 8 * h + j];
            qf[2 * j] = bflo(uq); qf[2 * j + 1] = bfhi(uq);
        }
#pragma unroll
        for (int s2 = 0; s2 < 12; ++s2) {
            int s0 = 2 * s2;
            float d0 = 0.f, d1 = 0.f;
#pragma unroll
            for (int j = 0; j < 8; ++j) {
                unsigned ka = s_qkv[1 * QKP + s0 * QKS + 8 * h + j];
                unsigned kb = s_qkv[1 * QKP + (s0 + 1) * QKS + 8 * h + j];
                d0 += qf[2 * j] * bflo(ka) + qf[2 * j + 1] * bfhi(ka);
                d1 += qf[2 * j] * bflo(kb) + qf[2 * j + 1] * bfhi(kb);
            }
            float w0 = (s0 <= t) ? __expf(d0 * scale) : 0.f;
            float w1 = (s0 + 1 <= t) ? __expf(d1 * scale) : 0.f;
            s_sc[(h * TT + t) * 13 + s2] = packbf(w0, w1);
        }
    }
    __syncthreads();

    // ---- phase C2: normalize + PV -> packed val[24][66]
    unsigned* s_val = arena + VAL_OFF;
#pragma unroll
    for (int it = 0; it < 3; ++it) {
        int item = tid + it * 256;             // < 768
        int h = item / 96;
        int r = item % 96;
        int t = r >> 2, d4 = r & 3;
        int kg0 = 8 * h + 2 * d4;
        float sum = 0.f, v0 = 0.f, v1 = 0.f, v2 = 0.f, v3 = 0.f;
#pragma unroll
        for (int s2 = 0; s2 < 12; ++s2) {
            unsigned uw = s_sc[(h * TT + t) * 13 + s2];
            float w0 = bflo(uw), w1 = bfhi(uw);
            sum += w0 + w1;
            unsigned ua = s_qkv[2 * QKP + (2 * s2) * QKS + kg0];
            unsigned ub = s_qkv[2 * QKP + (2 * s2) * QKS + kg0 + 1];
            v0 += w0 * bflo(ua); v1 += w0 * bfhi(ua);
            v2 += w0 * bflo(ub); v3 += w0 * bfhi(ub);
            unsigned uc = s_qkv[2 * QKP + (2 * s2 + 1) * QKS + kg0];
            unsigned ud = s_qkv[2 * QKP + (2 * s2 + 1) * QKS + kg0 + 1];
            v0 += w1 * bflo(uc); v1 += w1 * bfhi(uc);
            v2 += w1 * bflo(ud); v3 += w1 * bfhi(ud);
        }
        float inv = 1.f / sum;
        s_val[t * QKS + kg0]     = packbf(v0 * inv, v1 * inv);
        s_val[t * QKS + kg0 + 1] = packbf(v2 * inv, v3 * inv);
    }
    __syncthreads();

    // ---- phase D: value = lrelu(val @ out_w + out_b)
    for (int o = tid; o < TT * 16; o += 256) {
        int tq = o >> 4;
        int dd0 = (o & 15) * 4;
        float4 a = *(const float4*)&out_b[dd0];
        for (int j0 = 0; j0 < E2; j0 += 4) {
            unsigned xa = s_val[tq * QKS + j0 / 2];
            unsigned xb = s_val[tq * QKS + j0 / 2 + 1];
            float x0 = bflo(xa), x1 = bfhi(xa), x2 = bflo(xb), x3 = bfhi(xb);
            const float4 w0 = *(const float4*)&out_w[(j0 + 0) * DD + dd0];
            const float4 w1 = *(const float4*)&out_w[(j0 + 1) * DD + dd0];
            const float4 w2 = *(const float4*)&out_w[(j0 + 2) * DD + dd0];
            const float4 w3 = *(const float4*)&out_w[(j0 + 3) * DD + dd0];
            a.x += x0 * w0.x + x1 * w1.x + x2 * w2.x + x3 * w3.x;
            a.y += x0 * w0.y + x1 * w1.y + x2 * w2.y + x3 * w3.y;
            a.z += x0 * w0.z + x1 * w1.z + x2 * w2.z + x3 * w3.z;
            a.w += x0 * w0.w + x1 * w1.w + x2 * w2.w + x3 * w3.w;
        }
        a.x = (a.x >= 0.f) ? a.x : NEG * a.x;
        a.y = (a.y >= 0.f) ? a.y : NEG * a.y;
        a.z = (a.z >= 0.f) ? a.z : NEG * a.z;
        a.w = (a.w >= 0.f) ? a.w : NEG * a.w;
        *(float4*)&s_value[tq][dd0] = a;
    }
    __syncthreads();

    // ---- phase E: gate + residual
    for (int o = tid; o < TT * 16; o += 256) {
        int tq = o >> 4;
        int dd0 = (o & 15) * 4;
        float4 zz = *(const float4*)&gate_b[dd0];
        for (int j0 = 0; j0 < DD; j0 += 4) {
            const float4 x = *(const float4*)&s_gcn[tq][j0];
            const float4 w0 = *(const float4*)&gate_w[(j0 + 0) * DD + dd0];
            const float4 w1 = *(const float4*)&gate_w[(j0 + 1) * DD + dd0];
            const float4 w2 = *(const float4*)&gate_w[(j0 + 2) * DD + dd0];
            const float4 w3 = *(const float4*)&gate_w[(j0 + 3) * DD + dd0];
            zz.x += x.x * w0.x + x.y * w1.x + x.z * w2.x + x.w * w3.x;
            zz.y += x.x * w0.y + x.y * w1.y + x.z * w2.y + x.w * w3.y;
            zz.z += x.x * w0.z + x.y * w1.z + x.z * w2.z + x.w * w3.z;
            zz.w += x.x * w0.w + x.y * w1.w + x.z * w2.w + x.w * w3.w;
        }
        for (int j0 = 0; j0 < DD; j0 += 4) {
            const float4 x = *(const float4*)&s_value[tq][j0];
            const float4 w0 = *(const float4*)&gate_w[(DD + j0 + 0) * DD + dd0];
            const float4 w1 = *(const float4*)&gate_w[(DD + j0 + 1) * DD + dd0];
            const float4 w2 = *(const float4*)&gate_w[(DD + j0 + 2) * DD + dd0];
            const float4 w3 = *(const float4*)&gate_w[(DD + j0 + 3) * DD + dd0];
            zz.x += x.x * w0.x + x.y * w1.x + x.z * w2.x + x.w * w3.x;
            zz.y += x.x * w0.y + x.y * w1.y + x.z * w2.y + x.w * w3.y;
            zz.z += x.x * w0.z + x.y * w1.z + x.z * w2.z + x.w * w3.z;
            zz.w += x.x * w0.w + x.y * w1.w + x.z * w2.w + x.w * w3.w;
        }
        size_t ob = base + tq * DD + dd0;
        const float4 hv = *(const float4*)&hidden[ob];
        const float4 gv = *(const float4*)&s_gcn[tq][dd0];
        const float4 vv = *(const float4*)&s_value[tq][dd0];
        float4 oo;
        float z;
        z = 1.f / (1.f + __expf(-zz.x)); oo.x = z * gv.x + (1.f - z) * vv.x + hv.x;
        z = 1.f / (1.f + __expf(-zz.y)); oo.y = z * gv.y + (1.f - z) * vv.y + hv.y;
        z = 1.f / (1.f + __expf(-zz.z)); oo.z = z * gv.z + (1.f - z) * vv.z + hv.z;
        z = 1.f / (1.f + __expf(-zz.w)); oo.w = z * gv.w + (1.f - z) * vv.w + hv.w;
        *(float4*)&out[ob] = oo;
    }
}

extern "C" void kernel_launch(void* const* d_in, const int* in_sizes, int n_in,
                              void* d_out, int out_size, void* d_ws, size_t ws_size,
                              hipStream_t stream) {
    const float* hidden   = (const float*)d_in[0];
    const float* tXin     = (const float*)d_in[1];
    const float* matrix   = (const float*)d_in[2];
    const float* gcn_w    = (const float*)d_in[3];
    const float* gcn_b    = (const float*)d_in[4];
    const float* node_emb = (const float*)d_in[5];
    const float* tproj_w  = (const float*)d_in[6];
    const float* tproj_b  = (const float*)d_in[7];
    const float* WK_      = (const float*)d_in[8];   // dict order: WK, WQ, WV
    const float* WQ_      = (const float*)d_in[9];
    const float* WV_      = (const float*)d_in[10];
    const float* out_w    = (const float*)d_in[11];
    const float* out_b    = (const float*)d_in[12];
    const float* gate_w   = (const float*)d_in[13];
    const float* gate_b   = (const float*)d_in[14];
    float* out = (float*)d_out;

    char* ws = (char*)d_ws;
    float* tfeat   = (float*)ws;                         // 512 B
    float* gcn_out = (float*)(ws + 512);                 // 15,974,400 B
    size_t off_wp  = 512 + (size_t)BB * NN * TT * DD * 4;

    const size_t per_wp  = 3 * (size_t)E2 * E2 * 2;      // 98304 B per node (bf16)
    const size_t per_qkv = 3 * (size_t)TT * E2 * 2;      // 18432 B per node (bf16)
    long long avail = (long long)ws_size - (long long)off_wp;
    long long Ull = avail / (long long)(per_wp + per_qkv);
    int U = (Ull < 1) ? 1 : ((Ull > NNODE) ? NNODE : (int)Ull);

    unsigned short* wp_buf  = (unsigned short*)(ws + off_wp);
    unsigned short* qkv_buf = (unsigned short*)(ws + off_wp + (size_t)U * per_wp);

    k_tfeat<<<BB, DD, 0, stream>>>(tXin, tproj_w, tproj_b, tfeat);
    k_gcn<<<dim3(BB * TT, (NN + TN - 1) / TN), 256, 0, stream>>>(matrix, hidden, gcn_w, gcn_b, gcn_out);

    for (int u0 = 0; u0 < NNODE; u0 += U) {
        int Uc = (NNODE - u0 < U) ? (NNODE - u0) : U;
        k_wp<<<dim3((Uc + 15) / 16, 48), 256, 0, stream>>>(node_emb, tfeat, WQ_, WK_, WV_,
                                                           wp_buf, u0, Uc);
        k_proj<<<Uc, 256, 0, stream>>>(hidden, tXin, wp_buf, qkv_buf, u0);
        k_attn2<<<Uc, 256, 0, stream>>>((const unsigned*)qkv_buf, hidden, out_w, out_b,
                                        gate_w, gate_b, gcn_out, out, u0);
    }
}

// Round 11
// 495.882 us; speedup vs baseline: 2.9834x; 1.1692x over previous
//
#include <hip/hip_runtime.h>
#include <math.h>

#define BB 8
#define NN 325
#define TT 24
#define DD 64
#define HH 8
#define MM 16
#define E2 128
#define DK 16
#define NEG 0.1f
#define NNODE (BB * NN)          // 2600
#define HTM 328                  // padded m-extent of ht rows

typedef short bf16x8 __attribute__((ext_vector_type(8)));
typedef float f32x4 __attribute__((ext_vector_type(4)));

__device__ __forceinline__ unsigned short f2bf(float f) {
    union { float f; unsigned u; } v; v.f = f;
    unsigned r = v.u + 0x7fffu + ((v.u >> 16) & 1u);   // RNE
    return (unsigned short)(r >> 16);
}
__device__ __forceinline__ unsigned packbf(float a, float b) {
    return (unsigned)f2bf(a) | ((unsigned)f2bf(b) << 16);
}
__device__ __forceinline__ float bflo(unsigned u) { return __uint_as_float(u << 16); }
__device__ __forceinline__ float bfhi(unsigned u) { return __uint_as_float(u & 0xffff0000u); }

__device__ __forceinline__ bf16x8 pack_bf8(float4 lo, float4 hi) {
    bf16x8 r;
    r[0] = (short)f2bf(lo.x); r[1] = (short)f2bf(lo.y);
    r[2] = (short)f2bf(lo.z); r[3] = (short)f2bf(lo.w);
    r[4] = (short)f2bf(hi.x); r[5] = (short)f2bf(hi.y);
    r[6] = (short)f2bf(hi.z); r[7] = (short)f2bf(hi.w);
    return r;
}

// ---------------- K1: tfeat[b][m] = tanh(mean_t(tXin[b,0,t,:]) @ tproj_w + tproj_b)
__global__ void k_tfeat(const float* __restrict__ tXin, const float* __restrict__ tproj_w,
                        const float* __restrict__ tproj_b, float* __restrict__ tfeat) {
    int b = blockIdx.x;
    int d = threadIdx.x;  // 64 threads
    __shared__ float mv[DD];
    float a = 0.f;
    for (int t = 0; t < TT; ++t)
        a += tXin[((size_t)(b * NN + 0) * TT + t) * DD + d];
    mv[d] = a * (1.f / (float)TT);
    __syncthreads();
    if (d < MM) {
        float acc = tproj_b[d];
        for (int j = 0; j < DD; ++j) acc += mv[j] * tproj_w[j * MM + d];
        tfeat[b * MM + d] = tanhf(acc);
    }
}

// ---------------- K_ht: ht[bt][d][m] = bf16(hidden[b][m][t][d])  (transposed, padded to HTM)
// grid (192, 6); LDS-tiled transpose: coalesced f32 reads, contiguous u16 writes.
__global__ __launch_bounds__(256) void k_ht(const float* __restrict__ hidden,
                                            unsigned short* __restrict__ ht) {
    int bt = blockIdx.x;          // b*TT + t
    int b = bt / TT, t = bt % TT;
    int m0 = blockIdx.y * 64;
    __shared__ float s[64][67];   // stride 67: bank = 3j mod 32 -> conflict-free col reads
    int tid = threadIdx.x;
#pragma unroll
    for (int i = 0; i < 4; ++i) {
        int idx = tid + i * 256;          // 1024 float4 units
        int mm = idx >> 4, q = idx & 15;
        int m = m0 + mm;
        float4 v = make_float4(0.f, 0.f, 0.f, 0.f);
        if (m < NN) v = *(const float4*)&hidden[((size_t)(b * NN + m) * TT + t) * DD + q * 4];
        s[mm][q * 4 + 0] = v.x; s[mm][q * 4 + 1] = v.y;
        s[mm][q * 4 + 2] = v.z; s[mm][q * 4 + 3] = v.w;
    }
    __syncthreads();
    size_t obase = (size_t)bt * DD * HTM;
    int jcap = HTM - m0;
#pragma unroll
    for (int i = 0; i < 16; ++i) {
        int idx = tid + i * 256;          // 4096 u16 units
        int d = idx >> 6, j = idx & 63;
        if (j < jcap) ht[obase + (size_t)d * HTM + m0 + j] = f2bf(s[j][d]);
    }
}

// ---------------- K2 (MFMA): S = matrix(b,t) @ H ; gcn_out = relu(S @ gcn_w + b)
// grid (192, 6); 256 threads (4 waves), wave w owns rows [w*16, w*16+16) of the 64-row tile.
// A-fragments: guarded scalar loads from matrix (bf16-packed in-register).
// B-fragments: direct 16B global loads from ht (L2-resident). No LDS in K-loop.
__global__ __launch_bounds__(256) void k_gcn(const float* __restrict__ matrix,
                                             const unsigned short* __restrict__ ht,
                                             const float* __restrict__ gcn_w,
                                             const float* __restrict__ gcn_b,
                                             float* __restrict__ gcn_out) {
    int bt = blockIdx.x;
    int tile = blockIdx.y;
    int b = bt / TT, t = bt % TT;
    int n0 = tile * 64;
    int tid = threadIdx.x, lane = tid & 63, wid = tid >> 6;
    int cl = lane & 15, kg = lane >> 4;

    __shared__ unsigned short s_s[64][72];    // S bf16 [n][d]
    __shared__ unsigned short s_gw[64][72];   // gw^T bf16 [e][d]

    // stage gw transposed (once)
#pragma unroll
    for (int i = 0; i < 4; ++i) {
        int idx = tid + i * 256;
        int d = idx >> 4, e0 = (idx & 15) * 4;
        float4 v = *(const float4*)&gcn_w[d * DD + e0];
        s_gw[e0 + 0][d] = f2bf(v.x); s_gw[e0 + 1][d] = f2bf(v.y);
        s_gw[e0 + 2][d] = f2bf(v.z); s_gw[e0 + 3][d] = f2bf(v.w);
    }
    __syncthreads();

    const float* mrow = matrix + (size_t)bt * NN * NN;
    const unsigned short* hbase = ht + (size_t)bt * DD * HTM;
    int strip = wid * 16;
    int arow = n0 + strip + cl;
    bool avalid = arow < NN;
    const float* arp = mrow + (size_t)arow * NN;

    f32x4 acc[4];
#pragma unroll
    for (int nt = 0; nt < 4; ++nt) acc[nt] = (f32x4){0.f, 0.f, 0.f, 0.f};

#pragma unroll 1
    for (int ch = 0; ch < 5; ++ch) {
#pragma unroll
        for (int kk = 0; kk < 2; ++kk) {
            int m0 = ch * 64 + kk * 32 + kg * 8;   // <= 319, always < NN
            bf16x8 af = {0, 0, 0, 0, 0, 0, 0, 0};
            if (avalid) {
                float4 lo, hi;
                lo.x = arp[m0];     lo.y = arp[m0 + 1]; lo.z = arp[m0 + 2]; lo.w = arp[m0 + 3];
                hi.x = arp[m0 + 4]; hi.y = arp[m0 + 5]; hi.z = arp[m0 + 6]; hi.w = arp[m0 + 7];
                af = pack_bf8(lo, hi);
            }
#pragma unroll
            for (int nt = 0; nt < 4; ++nt) {
                union { uint4 u4; bf16x8 v; } bf;
                bf.u4 = *(const uint4*)&hbase[(size_t)(nt * 16 + cl) * HTM + m0];
                acc[nt] = __builtin_amdgcn_mfma_f32_16x16x32_bf16(af, bf.v, acc[nt], 0, 0, 0);
            }
        }
    }
    {   // tail chunk: m0 = 320 + kg*8, only m<325 valid in A (B garbage is nulled by A=0)
        int m0 = 320 + kg * 8;
        float v[8];
#pragma unroll
        for (int j = 0; j < 8; ++j)
            v[j] = (avalid && (m0 + j) < NN) ? arp[m0 + j] : 0.f;
        bf16x8 af = pack_bf8(make_float4(v[0], v[1], v[2], v[3]),
                             make_float4(v[4], v[5], v[6], v[7]));
#pragma unroll
        for (int nt = 0; nt < 4; ++nt) {
            union { uint4 u4; bf16x8 v4; } bf;
            bf.u4 = *(const uint4*)&hbase[(size_t)(nt * 16 + cl) * HTM + m0];
            acc[nt] = __builtin_amdgcn_mfma_f32_16x16x32_bf16(af, bf.v4, acc[nt], 0, 0, 0);
        }
    }

    // ---- S -> LDS bf16 (wave-private rows: no barrier needed before own re-reads)
#pragma unroll
    for (int nt = 0; nt < 4; ++nt)
#pragma unroll
        for (int r = 0; r < 4; ++r)
            s_s[strip + kg * 4 + r][nt * 16 + cl] = f2bf(acc[nt][r]);

    // ---- phase 2: gcn GEMM (K=64, 2 ksteps)
    f32x4 g[4];
#pragma unroll
    for (int nt = 0; nt < 4; ++nt) g[nt] = (f32x4){0.f, 0.f, 0.f, 0.f};
#pragma unroll
    for (int kk = 0; kk < 2; ++kk) {
        union { uint4 u4; bf16x8 v; } sa;
        sa.u4 = *(const uint4*)&s_s[strip + cl][kk * 32 + kg * 8];
#pragma unroll
        for (int nt = 0; nt < 4; ++nt) {
            union { uint4 u4; bf16x8 v; } bf;
            bf.u4 = *(const uint4*)&s_gw[nt * 16 + cl][kk * 32 + kg * 8];
            g[nt] = __builtin_amdgcn_mfma_f32_16x16x32_bf16(sa.v, bf.v, g[nt], 0, 0, 0);
        }
    }

    // ---- epilogue: bias + relu + store
#pragma unroll
    for (int nt = 0; nt < 4; ++nt) {
        float bias = gcn_b[nt * 16 + cl];
#pragma unroll
        for (int r = 0; r < 4; ++r) {
            int n = n0 + strip + kg * 4 + r;
            if (n < NN) {
                float v = g[nt][r] + bias;
                v = (v > 0.f) ? v : 0.f;
                gcn_out[((size_t)(b * NN + n) * TT + t) * DD + nt * 16 + cl] = v;
            }
        }
    }
}

// ---------------- K3a: Wp = sum_m e[m]*W[m], bf16 in MFMA B-fragment-major layout.
__global__ __launch_bounds__(256) void k_wp(
    const float* __restrict__ node_emb, const float* __restrict__ tfeat,
    const float* __restrict__ WQ, const float* __restrict__ WK, const float* __restrict__ WV,
    unsigned short* __restrict__ wp, int u0, int Uc) {
    int un0 = blockIdx.x * 16;
    int chunk = blockIdx.y;                 // 0..47
    int p = chunk >> 4;                     // 0=Q 1=K 2=V
    int c = chunk & 15;                     // i-block
    int off = c << 10;                      // 1024-elem chunk within 16384
    int tid = threadIdx.x;
    const float* __restrict__ W = (p == 0) ? WQ : ((p == 1) ? WK : WV);

    __shared__ float s_e[16][MM];
    __shared__ __align__(16) unsigned short s_out[16][1024];   // 32 KB

    {
        int nn = tid >> 4, m = tid & 15;    // 256 = 16*16 exactly
        int us = un0 + nn;
        float e = 0.f;
        if (us < Uc) {
            int u = u0 + us;
            int b = u / NN, n = u % NN;
            e = node_emb[n * MM + m] * tfeat[b * MM + m];
        }
        s_e[nn][m] = e;
    }
    __syncthreads();

    int j = off + tid * 4;                  // flat [i][k], k contiguous
    int k0 = j & 127;                       // output col, 4-aligned
    float4 acc[16];
#pragma unroll
    for (int nn = 0; nn < 16; ++nn) acc[nn] = make_float4(0.f, 0.f, 0.f, 0.f);
#pragma unroll
    for (int m = 0; m < MM; ++m) {
        float4 w = *(const float4*)&W[(size_t)m * 16384 + j];
#pragma unroll
        for (int nn = 0; nn < 16; ++nn) {
            float e = s_e[nn][m];
            acc[nn].x += e * w.x; acc[nn].y += e * w.y;
            acc[nn].z += e * w.z; acc[nn].w += e * w.w;
        }
    }

    // scatter bf16 into LDS (chunk-local fragment order: nt*128 + (k&15)*8 + jf)
    int nt = k0 >> 4;
    int jf = tid >> 5;                      // = i & 7
    int lb = nt * 128 + jf;
    int s0 = (k0 & 15) * 8;
#pragma unroll
    for (int nn = 0; nn < 16; ++nn) {
        s_out[nn][lb + s0]      = f2bf(acc[nn].x);
        s_out[nn][lb + s0 + 8]  = f2bf(acc[nn].y);
        s_out[nn][lb + s0 + 16] = f2bf(acc[nn].z);
        s_out[nn][lb + s0 + 24] = f2bf(acc[nn].w);
    }
    __syncthreads();

    // coalesced writeout: 2048 uint4 total, 8 per thread
    int ks = c >> 2, L = c & 3;
    size_t gbase = (size_t)p * 16384 + (size_t)ks * 512 + (size_t)L * 128;
#pragma unroll
    for (int ii = 0; ii < 8; ++ii) {
        int o = ii * 256 + tid;
        int node = o >> 7, r = o & 127;
        int ntw = r >> 4, w = r & 15;
        int us = un0 + node;
        if (us < Uc) {
            uint4 v = *(const uint4*)&s_out[node][ntw * 128 + w * 8];
            *(uint4*)&wp[(size_t)us * 49152 + gbase + (size_t)ntw * 2048 + w * 8] = v;
        }
    }
}

// ---------------- K3b: per node MFMA proj -> lrelu -> qkv bf16 to workspace.
__global__ __launch_bounds__(256) void k_proj(
    const float* __restrict__ hidden, const float* __restrict__ tXin,
    const unsigned short* __restrict__ wp, unsigned short* __restrict__ qkv,
    int u0) {
    int us = blockIdx.x;
    int u = u0 + us;
    int tid = threadIdx.x;
    int lane = tid & 63, wid = tid >> 6;
    int trow = lane & 15, kgrp = lane >> 4;

    size_t base = (size_t)u * TT * DD;

    bf16x8 afrag[2][4];
#pragma unroll
    for (int mt = 0; mt < 2; ++mt) {
        int t = mt * 16 + trow;
        bool valid = (t < TT);
#pragma unroll
        for (int ks = 0; ks < 4; ++ks) {
            int i0 = ks * 32 + kgrp * 8;
            float4 lo = make_float4(0.f, 0.f, 0.f, 0.f), hi = lo;
            if (valid) {
                const float* src = (i0 < DD) ? &hidden[base + t * DD + i0]
                                             : &tXin[base + t * DD + (i0 - DD)];
                lo = *(const float4*)src;
                hi = *(const float4*)(src + 4);
            }
            afrag[mt][ks] = pack_bf8(lo, hi);
        }
    }

    const unsigned short* wbase = wp + (size_t)us * 49152;
    unsigned short* qbase = qkv + (size_t)us * (3 * TT * E2);
    int rowg = kgrp * 4;
    int col0 = wid * 16 + trow;
    int col1 = (wid + 4) * 16 + trow;
#pragma unroll 1
    for (int p = 0; p < 3; ++p) {
        f32x4 acc00 = {0.f, 0.f, 0.f, 0.f}, acc01 = acc00, acc10 = acc00, acc11 = acc00;
#pragma unroll
        for (int ks = 0; ks < 4; ++ks) {
            union { uint4 u4; bf16x8 v; } c0, c1;
            c0.u4 = *(const uint4*)(wbase + (size_t)p * 16384 + (((wid) * 4 + ks) * 64 + lane) * 8);
            c1.u4 = *(const uint4*)(wbase + (size_t)p * 16384 + (((wid + 4) * 4 + ks) * 64 + lane) * 8);
            acc00 = __builtin_amdgcn_mfma_f32_16x16x32_bf16(afrag[0][ks], c0.v, acc00, 0, 0, 0);
            acc10 = __builtin_amdgcn_mfma_f32_16x16x32_bf16(afrag[1][ks], c0.v, acc10, 0, 0, 0);
            acc01 = __builtin_amdgcn_mfma_f32_16x16x32_bf16(afrag[0][ks], c1.v, acc01, 0, 0, 0);
            acc11 = __builtin_amdgcn_mfma_f32_16x16x32_bf16(afrag[1][ks], c1.v, acc11, 0, 0, 0);
        }
#pragma unroll
        for (int r = 0; r < 4; ++r) {
            int t = rowg + r;
            float v0 = acc00[r]; v0 = (v0 >= 0.f) ? v0 : NEG * v0;
            float v1 = acc01[r]; v1 = (v1 >= 0.f) ? v1 : NEG * v1;
            qbase[(p * TT + t) * E2 + col0] = f2bf(v0);
            qbase[(p * TT + t) * E2 + col1] = f2bf(v1);
        }
        if (rowg < 8) {
#pragma unroll
            for (int r = 0; r < 4; ++r) {
                int t = 16 + rowg + r;
                float v0 = acc10[r]; v0 = (v0 >= 0.f) ? v0 : NEG * v0;
                float v1 = acc11[r]; v1 = (v1 >= 0.f) ? v1 : NEG * v1;
                qbase[(p * TT + t) * E2 + col0] = f2bf(v0);
                qbase[(p * TT + t) * E2 + col1] = f2bf(v1);
            }
        }
    }
}

// ---------------- K3c: per node: attention + out-proj + gate + residual (verified phases)
#define QKS 66
#define QKP (TT * QKS)          // 1584 u32 per proj plane
#define SC_OFF 4752
#define VAL_OFF 7248
__global__ __launch_bounds__(256) void k_attn2(
    const unsigned* __restrict__ qkv, const float* __restrict__ hidden,
    const float* __restrict__ out_w, const float* __restrict__ out_b,
    const float* __restrict__ gate_w, const float* __restrict__ gate_b,
    const float* __restrict__ gcn_out, float* __restrict__ out,
    int u0) {
    int us = blockIdx.x;
    int u = u0 + us;
    int tid = threadIdx.x;

    __shared__ __align__(16) unsigned arena[8832];
    __shared__ float s_gcn[TT][68];
    __shared__ float s_value[TT][68];

    size_t base = (size_t)u * TT * DD;

    const unsigned* src = qkv + (size_t)us * (3 * TT * 64);
    for (int idx = tid; idx < 3 * TT * 64; idx += 256) {
        int p = idx / (TT * 64);
        int r = idx % (TT * 64);
        int t = r >> 6, kp = r & 63;
        arena[p * QKP + t * QKS + kp] = src[idx];
    }
    for (int idx = tid; idx < TT * DD; idx += 256)
        s_gcn[idx >> 6][idx & 63] = gcn_out[base + idx];
    unsigned* s_qkv = arena;
    __syncthreads();

    unsigned* s_sc = arena + SC_OFF;
    if (tid < HH * TT) {
        int h = tid / TT, t = tid % TT;
        const float scale = 0.25f;
        float qf[16];
#pragma unroll
        for (int j = 0; j < 8; ++j) {
            unsigned uq = s_qkv[0 * QKP + t * QKS + 8 * h + j];
            qf[2 * j] = bflo(uq); qf[2 * j + 1] = bfhi(uq);
        }
#pragma unroll
        for (int s2 = 0; s2 < 12; ++s2) {
            int s0 = 2 * s2;
            float d0 = 0.f, d1 = 0.f;
#pragma unroll
            for (int j = 0; j < 8; ++j) {
                unsigned ka = s_qkv[1 * QKP + s0 * QKS + 8 * h + j];
                unsigned kb = s_qkv[1 * QKP + (s0 + 1) * QKS + 8 * h + j];
                d0 += qf[2 * j] * bflo(ka) + qf[2 * j + 1] * bfhi(ka);
                d1 += qf[2 * j] * bflo(kb) + qf[2 * j + 1] * bfhi(kb);
            }
            float w0 = (s0 <= t) ? __expf(d0 * scale) : 0.f;
            float w1 = (s0 + 1 <= t) ? __expf(d1 * scale) : 0.f;
            s_sc[(h * TT + t) * 13 + s2] = packbf(w0, w1);
        }
    }
    __syncthreads();

    unsigned* s_val = arena + VAL_OFF;
#pragma unroll
    for (int it = 0; it < 3; ++it) {
        int item = tid + it * 256;
        int h = item / 96;
        int r = item % 96;
        int t = r >> 2, d4 = r & 3;
        int kg0 = 8 * h + 2 * d4;
        float sum = 0.f, v0 = 0.f, v1 = 0.f, v2 = 0.f, v3 = 0.f;
#pragma unroll
        for (int s2 = 0; s2 < 12; ++s2) {
            unsigned uw = s_sc[(h * TT + t) * 13 + s2];
            float w0 = bflo(uw), w1 = bfhi(uw);
            sum += w0 + w1;
            unsigned ua = s_qkv[2 * QKP + (2 * s2) * QKS + kg0];
            unsigned ub = s_qkv[2 * QKP + (2 * s2) * QKS + kg0 + 1];
            v0 += w0 * bflo(ua); v1 += w0 * bfhi(ua);
            v2 += w0 * bflo(ub); v3 += w0 * bfhi(ub);
            unsigned uc = s_qkv[2 * QKP + (2 * s2 + 1) * QKS + kg0];
            unsigned ud = s_qkv[2 * QKP + (2 * s2 + 1) * QKS + kg0 + 1];
            v0 += w1 * bflo(uc); v1 += w1 * bfhi(uc);
            v2 += w1 * bflo(ud); v3 += w1 * bfhi(ud);
        }
        float inv = 1.f / sum;
        s_val[t * QKS + kg0]     = packbf(v0 * inv, v1 * inv);
        s_val[t * QKS + kg0 + 1] = packbf(v2 * inv, v3 * inv);
    }
    __syncthreads();

    for (int o = tid; o < TT * 16; o += 256) {
        int tq = o >> 4;
        int dd0 = (o & 15) * 4;
        float4 a = *(const float4*)&out_b[dd0];
        for (int j0 = 0; j0 < E2; j0 += 4) {
            unsigned xa = s_val[tq * QKS + j0 / 2];
            unsigned xb = s_val[tq * QKS + j0 / 2 + 1];
            float x0 = bflo(xa), x1 = bfhi(xa), x2 = bflo(xb), x3 = bfhi(xb);
            const float4 w0 = *(const float4*)&out_w[(j0 + 0) * DD + dd0];
            const float4 w1 = *(const float4*)&out_w[(j0 + 1) * DD + dd0];
            const float4 w2 = *(const float4*)&out_w[(j0 + 2) * DD + dd0];
            const float4 w3 = *(const float4*)&out_w[(j0 + 3) * DD + dd0];
            a.x += x0 * w0.x + x1 * w1.x + x2 * w2.x + x3 * w3.x;
            a.y += x0 * w0.y + x1 * w1.y + x2 * w2.y + x3 * w3.y;
            a.z += x0 * w0.z + x1 * w1.z + x2 * w2.z + x3 * w3.z;
            a.w += x0 * w0.w + x1 * w1.w + x2 * w2.w + x3 * w3.w;
        }
        a.x = (a.x >= 0.f) ? a.x : NEG * a.x;
        a.y = (a.y >= 0.f) ? a.y : NEG * a.y;
        a.z = (a.z >= 0.f) ? a.z : NEG * a.z;
        a.w = (a.w >= 0.f) ? a.w : NEG * a.w;
        *(float4*)&s_value[tq][dd0] = a;
    }
    __syncthreads();

    for (int o = tid; o < TT * 16; o += 256) {
        int tq = o >> 4;
        int dd0 = (o & 15) * 4;
        float4 zz = *(const float4*)&gate_b[dd0];
        for (int j0 = 0; j0 < DD; j0 += 4) {
            const float4 x = *(const float4*)&s_gcn[tq][j0];
            const float4 w0 = *(const float4*)&gate_w[(j0 + 0) * DD + dd0];
            const float4 w1 = *(const float4*)&gate_w[(j0 + 1) * DD + dd0];
            const float4 w2 = *(const float4*)&gate_w[(j0 + 2) * DD + dd0];
            const float4 w3 = *(const float4*)&gate_w[(j0 + 3) * DD + dd0];
            zz.x += x.x * w0.x + x.y * w1.x + x.z * w2.x + x.w * w3.x;
            zz.y += x.x * w0.y + x.y * w1.y + x.z * w2.y + x.w * w3.y;
            zz.z += x.x * w0.z + x.y * w1.z + x.z * w2.z + x.w * w3.z;
            zz.w += x.x * w0.w + x.y * w1.w + x.z * w2.w + x.w * w3.w;
        }
        for (int j0 = 0; j0 < DD; j0 += 4) {
            const float4 x = *(const float4*)&s_value[tq][j0];
            const float4 w0 = *(const float4*)&gate_w[(DD + j0 + 0) * DD + dd0];
            const float4 w1 = *(const float4*)&gate_w[(DD + j0 + 1) * DD + dd0];
            const float4 w2 = *(const float4*)&gate_w[(DD + j0 + 2) * DD + dd0];
            const float4 w3 = *(const float4*)&gate_w[(DD + j0 + 3) * DD + dd0];
            zz.x += x.x * w0.x + x.y * w1.x + x.z * w2.x + x.w * w3.x;
            zz.y += x.x * w0.y + x.y * w1.y + x.z * w2.y + x.w * w3.y;
            zz.z += x.x * w0.z + x.y * w1.z + x.z * w2.z + x.w * w3.z;
            zz.w += x.x * w0.w + x.y * w1.w + x.z * w2.w + x.w * w3.w;
        }
        size_t ob = base + tq * DD + dd0;
        const float4 hv = *(const float4*)&hidden[ob];
        const float4 gv = *(const float4*)&s_gcn[tq][dd0];
        const float4 vv = *(const float4*)&s_value[tq][dd0];
        float4 oo;
        float z;
        z = 1.f / (1.f + __expf(-zz.x)); oo.x = z * gv.x + (1.f - z) * vv.x + hv.x;
        z = 1.f / (1.f + __expf(-zz.y)); oo.y = z * gv.y + (1.f - z) * vv.y + hv.y;
        z = 1.f / (1.f + __expf(-zz.z)); oo.z = z * gv.z + (1.f - z) * vv.z + hv.z;
        z = 1.f / (1.f + __expf(-zz.w)); oo.w = z * gv.w + (1.f - z) * vv.w + hv.w;
        *(float4*)&out[ob] = oo;
    }
}

extern "C" void kernel_launch(void* const* d_in, const int* in_sizes, int n_in,
                              void* d_out, int out_size, void* d_ws, size_t ws_size,
                              hipStream_t stream) {
    const float* hidden   = (const float*)d_in[0];
    const float* tXin     = (const float*)d_in[1];
    const float* matrix   = (const float*)d_in[2];
    const float* gcn_w    = (const float*)d_in[3];
    const float* gcn_b    = (const float*)d_in[4];
    const float* node_emb = (const float*)d_in[5];
    const float* tproj_w  = (const float*)d_in[6];
    const float* tproj_b  = (const float*)d_in[7];
    const float* WK_      = (const float*)d_in[8];   // dict order: WK, WQ, WV
    const float* WQ_      = (const float*)d_in[9];
    const float* WV_      = (const float*)d_in[10];
    const float* out_w    = (const float*)d_in[11];
    const float* out_b    = (const float*)d_in[12];
    const float* gate_w   = (const float*)d_in[13];
    const float* gate_b   = (const float*)d_in[14];
    float* out = (float*)d_out;

    char* ws = (char*)d_ws;
    float* tfeat   = (float*)ws;                         // 512 B
    float* gcn_out = (float*)(ws + 512);                 // 15,974,400 B
    size_t off_ht  = 512 + (size_t)BB * NN * TT * DD * 4;          // 15,974,912
    size_t ht_size = (size_t)BB * TT * DD * HTM * 2 + 4096;        // 8,065,024 (incl. slack)
    size_t off_wp  = off_ht + ht_size;

    const size_t per_wp  = 3 * (size_t)E2 * E2 * 2;      // 98304 B per node (bf16)
    const size_t per_qkv = 3 * (size_t)TT * E2 * 2;      // 18432 B per node (bf16)
    long long avail = (long long)ws_size - (long long)off_wp;
    long long Ull = avail / (long long)(per_wp + per_qkv);
    int U = (Ull < 1) ? 1 : ((Ull > NNODE) ? NNODE : (int)Ull);

    unsigned short* ht_buf  = (unsigned short*)(ws + off_ht);
    unsigned short* wp_buf  = (unsigned short*)(ws + off_wp);
    unsigned short* qkv_buf = (unsigned short*)(ws + off_wp + (size_t)U * per_wp);

    k_tfeat<<<BB, DD, 0, stream>>>(tXin, tproj_w, tproj_b, tfeat);
    k_ht<<<dim3(BB * TT, 6), 256, 0, stream>>>(hidden, ht_buf);
    k_gcn<<<dim3(BB * TT, 6), 256, 0, stream>>>(matrix, ht_buf, gcn_w, gcn_b, gcn_out);

    for (int u0 = 0; u0 < NNODE; u0 += U) {
        int Uc = (NNODE - u0 < U) ? (NNODE - u0) : U;
        k_wp<<<dim3((Uc + 15) / 16, 48), 256, 0, stream>>>(node_emb, tfeat, WQ_, WK_, WV_,
                                                           wp_buf, u0, Uc);
        k_proj<<<Uc, 256, 0, stream>>>(hidden, tXin, wp_buf, qkv_buf, u0);
        k_attn2<<<Uc, 256, 0, stream>>>((const unsigned*)qkv_buf, hidden, out_w, out_b,
                                        gate_w, gate_b, gcn_out, out, u0);
    }
}

// Round 12
// 388.778 us; speedup vs baseline: 3.8052x; 1.2755x over previous
//
#include <hip/hip_runtime.h>
#include <math.h>

#define BB 8
#define NN 325
#define TT 24
#define DD 64
#define HH 8
#define MM 16
#define E2 128
#define DK 16
#define NEG 0.1f
#define NNODE (BB * NN)          // 2600
#define HTM 328                  // padded m-extent of ht rows

typedef short bf16x8 __attribute__((ext_vector_type(8)));
typedef float f32x4 __attribute__((ext_vector_type(4)));

__device__ __forceinline__ unsigned short f2bf(float f) {
    union { float f; unsigned u; } v; v.f = f;
    unsigned r = v.u + 0x7fffu + ((v.u >> 16) & 1u);   // RNE
    return (unsigned short)(r >> 16);
}
__device__ __forceinline__ unsigned packbf(float a, float b) {
    return (unsigned)f2bf(a) | ((unsigned)f2bf(b) << 16);
}
__device__ __forceinline__ float bflo(unsigned u) { return __uint_as_float(u << 16); }
__device__ __forceinline__ float bfhi(unsigned u) { return __uint_as_float(u & 0xffff0000u); }

__device__ __forceinline__ bf16x8 pack_bf8(float4 lo, float4 hi) {
    bf16x8 r;
    r[0] = (short)f2bf(lo.x); r[1] = (short)f2bf(lo.y);
    r[2] = (short)f2bf(lo.z); r[3] = (short)f2bf(lo.w);
    r[4] = (short)f2bf(hi.x); r[5] = (short)f2bf(hi.y);
    r[6] = (short)f2bf(hi.z); r[7] = (short)f2bf(hi.w);
    return r;
}

// ---------------- K1: tfeat[b][m] = tanh(mean_t(tXin[b,0,t,:]) @ tproj_w + tproj_b)
__global__ void k_tfeat(const float* __restrict__ tXin, const float* __restrict__ tproj_w,
                        const float* __restrict__ tproj_b, float* __restrict__ tfeat) {
    int b = blockIdx.x;
    int d = threadIdx.x;  // 64 threads
    __shared__ float mv[DD];
    float a = 0.f;
    for (int t = 0; t < TT; ++t)
        a += tXin[((size_t)(b * NN + 0) * TT + t) * DD + d];
    mv[d] = a * (1.f / (float)TT);
    __syncthreads();
    if (d < MM) {
        float acc = tproj_b[d];
        for (int j = 0; j < DD; ++j) acc += mv[j] * tproj_w[j * MM + d];
        tfeat[b * MM + d] = tanhf(acc);
    }
}

// ---------------- K_cw: out_w/gate_w -> bf16 B-fragment layout (once, 1 block)
// element (i,k) -> u16 off = (nt*4+ks)*512 + lane*8 + jf; nt=k>>4, ks=i>>5,
// lane=(k&15)|(((i>>3)&3)<<4), jf=i&7.  cw[0:8192]=out_w, cw[8192:16384]=gate_w.
__global__ __launch_bounds__(256) void k_cw(const float* __restrict__ out_w,
                                            const float* __restrict__ gate_w,
                                            unsigned short* __restrict__ cw) {
    int tid = threadIdx.x;
    for (int idx = tid; idx < 8192; idx += 256) {
        int i = idx >> 6, k = idx & 63;
        int nt = k >> 4, ks = i >> 5;
        int lane = (k & 15) | (((i >> 3) & 3) << 4);
        int off = (nt * 4 + ks) * 512 + lane * 8 + (i & 7);
        cw[off] = f2bf(out_w[i * 64 + k]);
        cw[8192 + off] = f2bf(gate_w[i * 64 + k]);
    }
}

// ---------------- K_ht: ht[bt][d][m] = bf16(hidden[b][m][t][d])  (transposed, padded to HTM)
__global__ __launch_bounds__(256) void k_ht(const float* __restrict__ hidden,
                                            unsigned short* __restrict__ ht) {
    int bt = blockIdx.x;          // b*TT + t
    int b = bt / TT, t = bt % TT;
    int m0 = blockIdx.y * 64;
    __shared__ float s[64][67];
    int tid = threadIdx.x;
#pragma unroll
    for (int i = 0; i < 4; ++i) {
        int idx = tid + i * 256;
        int mm = idx >> 4, q = idx & 15;
        int m = m0 + mm;
        float4 v = make_float4(0.f, 0.f, 0.f, 0.f);
        if (m < NN) v = *(const float4*)&hidden[((size_t)(b * NN + m) * TT + t) * DD + q * 4];
        s[mm][q * 4 + 0] = v.x; s[mm][q * 4 + 1] = v.y;
        s[mm][q * 4 + 2] = v.z; s[mm][q * 4 + 3] = v.w;
    }
    __syncthreads();
    size_t obase = (size_t)bt * DD * HTM;
    int jcap = HTM - m0;
#pragma unroll
    for (int i = 0; i < 16; ++i) {
        int idx = tid + i * 256;
        int d = idx >> 6, j = idx & 63;
        if (j < jcap) ht[obase + (size_t)d * HTM + m0 + j] = f2bf(s[j][d]);
    }
}

// ---------------- K2 (MFMA): S = matrix(b,t) @ H ; gcn_out = relu(S @ gcn_w + b)
__global__ __launch_bounds__(256) void k_gcn(const float* __restrict__ matrix,
                                             const unsigned short* __restrict__ ht,
                                             const float* __restrict__ gcn_w,
                                             const float* __restrict__ gcn_b,
                                             float* __restrict__ gcn_out) {
    int bt = blockIdx.x;
    int tile = blockIdx.y;
    int b = bt / TT, t = bt % TT;
    int n0 = tile * 64;
    int tid = threadIdx.x, lane = tid & 63, wid = tid >> 6;
    int cl = lane & 15, kg = lane >> 4;

    __shared__ unsigned short s_s[64][72];    // S bf16 [n][d]
    __shared__ unsigned short s_gw[64][72];   // gw^T bf16 [e][d]

#pragma unroll
    for (int i = 0; i < 4; ++i) {
        int idx = tid + i * 256;
        int d = idx >> 4, e0 = (idx & 15) * 4;
        float4 v = *(const float4*)&gcn_w[d * DD + e0];
        s_gw[e0 + 0][d] = f2bf(v.x); s_gw[e0 + 1][d] = f2bf(v.y);
        s_gw[e0 + 2][d] = f2bf(v.z); s_gw[e0 + 3][d] = f2bf(v.w);
    }
    __syncthreads();

    const float* mrow = matrix + (size_t)bt * NN * NN;
    const unsigned short* hbase = ht + (size_t)bt * DD * HTM;
    int strip = wid * 16;
    int arow = n0 + strip + cl;
    bool avalid = arow < NN;
    const float* arp = mrow + (size_t)arow * NN;

    f32x4 acc[4];
#pragma unroll
    for (int nt = 0; nt < 4; ++nt) acc[nt] = (f32x4){0.f, 0.f, 0.f, 0.f};

#pragma unroll 1
    for (int ch = 0; ch < 5; ++ch) {
#pragma unroll
        for (int kk = 0; kk < 2; ++kk) {
            int m0 = ch * 64 + kk * 32 + kg * 8;
            bf16x8 af = {0, 0, 0, 0, 0, 0, 0, 0};
            if (avalid) {
                float4 lo, hi;
                lo.x = arp[m0];     lo.y = arp[m0 + 1]; lo.z = arp[m0 + 2]; lo.w = arp[m0 + 3];
                hi.x = arp[m0 + 4]; hi.y = arp[m0 + 5]; hi.z = arp[m0 + 6]; hi.w = arp[m0 + 7];
                af = pack_bf8(lo, hi);
            }
#pragma unroll
            for (int nt = 0; nt < 4; ++nt) {
                union { uint4 u4; bf16x8 v; } bf;
                bf.u4 = *(const uint4*)&hbase[(size_t)(nt * 16 + cl) * HTM + m0];
                acc[nt] = __builtin_amdgcn_mfma_f32_16x16x32_bf16(af, bf.v, acc[nt], 0, 0, 0);
            }
        }
    }
    {
        int m0 = 320 + kg * 8;
        float v[8];
#pragma unroll
        for (int j = 0; j < 8; ++j)
            v[j] = (avalid && (m0 + j) < NN) ? arp[m0 + j] : 0.f;
        bf16x8 af = pack_bf8(make_float4(v[0], v[1], v[2], v[3]),
                             make_float4(v[4], v[5], v[6], v[7]));
#pragma unroll
        for (int nt = 0; nt < 4; ++nt) {
            union { uint4 u4; bf16x8 v4; } bf;
            bf.u4 = *(const uint4*)&hbase[(size_t)(nt * 16 + cl) * HTM + m0];
            acc[nt] = __builtin_amdgcn_mfma_f32_16x16x32_bf16(af, bf.v4, acc[nt], 0, 0, 0);
        }
    }

#pragma unroll
    for (int nt = 0; nt < 4; ++nt)
#pragma unroll
        for (int r = 0; r < 4; ++r)
            s_s[strip + kg * 4 + r][nt * 16 + cl] = f2bf(acc[nt][r]);

    f32x4 g[4];
#pragma unroll
    for (int nt = 0; nt < 4; ++nt) g[nt] = (f32x4){0.f, 0.f, 0.f, 0.f};
#pragma unroll
    for (int kk = 0; kk < 2; ++kk) {
        union { uint4 u4; bf16x8 v; } sa;
        sa.u4 = *(const uint4*)&s_s[strip + cl][kk * 32 + kg * 8];
#pragma unroll
        for (int nt = 0; nt < 4; ++nt) {
            union { uint4 u4; bf16x8 v; } bf;
            bf.u4 = *(const uint4*)&s_gw[nt * 16 + cl][kk * 32 + kg * 8];
            g[nt] = __builtin_amdgcn_mfma_f32_16x16x32_bf16(sa.v, bf.v, g[nt], 0, 0, 0);
        }
    }

#pragma unroll
    for (int nt = 0; nt < 4; ++nt) {
        float bias = gcn_b[nt * 16 + cl];
#pragma unroll
        for (int r = 0; r < 4; ++r) {
            int n = n0 + strip + kg * 4 + r;
            if (n < NN) {
                float v = g[nt][r] + bias;
                v = (v > 0.f) ? v : 0.f;
                gcn_out[((size_t)(b * NN + n) * TT + t) * DD + nt * 16 + cl] = v;
            }
        }
    }
}

// ---------------- K3a: Wp = sum_m e[m]*W[m], bf16 in MFMA B-fragment-major layout.
__global__ __launch_bounds__(256) void k_wp(
    const float* __restrict__ node_emb, const float* __restrict__ tfeat,
    const float* __restrict__ WQ, const float* __restrict__ WK, const float* __restrict__ WV,
    unsigned short* __restrict__ wp, int u0, int Uc) {
    int un0 = blockIdx.x * 16;
    int chunk = blockIdx.y;                 // 0..47
    int p = chunk >> 4;                     // 0=Q 1=K 2=V
    int c = chunk & 15;                     // i-block
    int off = c << 10;
    int tid = threadIdx.x;
    const float* __restrict__ W = (p == 0) ? WQ : ((p == 1) ? WK : WV);

    __shared__ float s_e[16][MM];
    __shared__ __align__(16) unsigned short s_out[16][1024];   // 32 KB

    {
        int nn = tid >> 4, m = tid & 15;
        int us = un0 + nn;
        float e = 0.f;
        if (us < Uc) {
            int u = u0 + us;
            int b = u / NN, n = u % NN;
            e = node_emb[n * MM + m] * tfeat[b * MM + m];
        }
        s_e[nn][m] = e;
    }
    __syncthreads();

    int j = off + tid * 4;
    int k0 = j & 127;
    float4 acc[16];
#pragma unroll
    for (int nn = 0; nn < 16; ++nn) acc[nn] = make_float4(0.f, 0.f, 0.f, 0.f);
#pragma unroll
    for (int m = 0; m < MM; ++m) {
        float4 w = *(const float4*)&W[(size_t)m * 16384 + j];
#pragma unroll
        for (int nn = 0; nn < 16; ++nn) {
            float e = s_e[nn][m];
            acc[nn].x += e * w.x; acc[nn].y += e * w.y;
            acc[nn].z += e * w.z; acc[nn].w += e * w.w;
        }
    }

    int nt = k0 >> 4;
    int jf = tid >> 5;
    int lb = nt * 128 + jf;
    int s0 = (k0 & 15) * 8;
#pragma unroll
    for (int nn = 0; nn < 16; ++nn) {
        s_out[nn][lb + s0]      = f2bf(acc[nn].x);
        s_out[nn][lb + s0 + 8]  = f2bf(acc[nn].y);
        s_out[nn][lb + s0 + 16] = f2bf(acc[nn].z);
        s_out[nn][lb + s0 + 24] = f2bf(acc[nn].w);
    }
    __syncthreads();

    int ks = c >> 2, L = c & 3;
    size_t gbase = (size_t)p * 16384 + (size_t)ks * 512 + (size_t)L * 128;
#pragma unroll
    for (int ii = 0; ii < 8; ++ii) {
        int o = ii * 256 + tid;
        int node = o >> 7, r = o & 127;
        int ntw = r >> 4, w = r & 15;
        int us = un0 + node;
        if (us < Uc) {
            uint4 v = *(const uint4*)&s_out[node][ntw * 128 + w * 8];
            *(uint4*)&wp[(size_t)us * 49152 + gbase + (size_t)ntw * 2048 + w * 8] = v;
        }
    }
}

// ---------------- K3b: per node MFMA proj -> lrelu -> qkv bf16 to workspace.
__global__ __launch_bounds__(256) void k_proj(
    const float* __restrict__ hidden, const float* __restrict__ tXin,
    const unsigned short* __restrict__ wp, unsigned short* __restrict__ qkv,
    int u0) {
    int us = blockIdx.x;
    int u = u0 + us;
    int tid = threadIdx.x;
    int lane = tid & 63, wid = tid >> 6;
    int trow = lane & 15, kgrp = lane >> 4;

    size_t base = (size_t)u * TT * DD;

    bf16x8 afrag[2][4];
#pragma unroll
    for (int mt = 0; mt < 2; ++mt) {
        int t = mt * 16 + trow;
        bool valid = (t < TT);
#pragma unroll
        for (int ks = 0; ks < 4; ++ks) {
            int i0 = ks * 32 + kgrp * 8;
            float4 lo = make_float4(0.f, 0.f, 0.f, 0.f), hi = lo;
            if (valid) {
                const float* src = (i0 < DD) ? &hidden[base + t * DD + i0]
                                             : &tXin[base + t * DD + (i0 - DD)];
                lo = *(const float4*)src;
                hi = *(const float4*)(src + 4);
            }
            afrag[mt][ks] = pack_bf8(lo, hi);
        }
    }

    const unsigned short* wbase = wp + (size_t)us * 49152;
    unsigned short* qbase = qkv + (size_t)us * (3 * TT * E2);
    int rowg = kgrp * 4;
    int col0 = wid * 16 + trow;
    int col1 = (wid + 4) * 16 + trow;
#pragma unroll 1
    for (int p = 0; p < 3; ++p) {
        f32x4 acc00 = {0.f, 0.f, 0.f, 0.f}, acc01 = acc00, acc10 = acc00, acc11 = acc00;
#pragma unroll
        for (int ks = 0; ks < 4; ++ks) {
            union { uint4 u4; bf16x8 v; } c0, c1;
            c0.u4 = *(const uint4*)(wbase + (size_t)p * 16384 + (((wid) * 4 + ks) * 64 + lane) * 8);
            c1.u4 = *(const uint4*)(wbase + (size_t)p * 16384 + (((wid + 4) * 4 + ks) * 64 + lane) * 8);
            acc00 = __builtin_amdgcn_mfma_f32_16x16x32_bf16(afrag[0][ks], c0.v, acc00, 0, 0, 0);
            acc10 = __builtin_amdgcn_mfma_f32_16x16x32_bf16(afrag[1][ks], c0.v, acc10, 0, 0, 0);
            acc01 = __builtin_amdgcn_mfma_f32_16x16x32_bf16(afrag[0][ks], c1.v, acc01, 0, 0, 0);
            acc11 = __builtin_amdgcn_mfma_f32_16x16x32_bf16(afrag[1][ks], c1.v, acc11, 0, 0, 0);
        }
#pragma unroll
        for (int r = 0; r < 4; ++r) {
            int t = rowg + r;
            float v0 = acc00[r]; v0 = (v0 >= 0.f) ? v0 : NEG * v0;
            float v1 = acc01[r]; v1 = (v1 >= 0.f) ? v1 : NEG * v1;
            qbase[(p * TT + t) * E2 + col0] = f2bf(v0);
            qbase[(p * TT + t) * E2 + col1] = f2bf(v1);
        }
        if (rowg < 8) {
#pragma unroll
            for (int r = 0; r < 4; ++r) {
                int t = 16 + rowg + r;
                float v0 = acc10[r]; v0 = (v0 >= 0.f) ? v0 : NEG * v0;
                float v1 = acc11[r]; v1 = (v1 >= 0.f) ? v1 : NEG * v1;
                qbase[(p * TT + t) * E2 + col0] = f2bf(v0);
                qbase[(p * TT + t) * E2 + col1] = f2bf(v1);
            }
        }
    }
}

// ---------------- K3c: per node: attention (scalar C1/C2) + MFMA out-proj/gate + residual
// arena u32[8880]: qkv u32[3][24][66] @0 | sc u32[8][24][13] @4752 | val u32[24][68] @7248
#define QKS 66
#define QKP (TT * QKS)
#define SC_OFF 4752
#define VAL_OFF 7248
#define VQS 68
__global__ __launch_bounds__(256) void k_attn2(
    const unsigned* __restrict__ qkv, const float* __restrict__ hidden,
    const unsigned short* __restrict__ cw,
    const float* __restrict__ out_b, const float* __restrict__ gate_b,
    const float* __restrict__ gcn_out, float* __restrict__ out,
    int u0) {
    int us = blockIdx.x;
    int u = u0 + us;
    int tid = threadIdx.x;

    __shared__ __align__(16) unsigned arena[8880];
    __shared__ float s_gcn[TT][VQS];
    __shared__ float s_value[TT][VQS];

    size_t base = (size_t)u * TT * DD;

    const unsigned* src = qkv + (size_t)us * (3 * TT * 64);
    for (int idx = tid; idx < 3 * TT * 64; idx += 256) {
        int p = idx / (TT * 64);
        int r = idx % (TT * 64);
        int t = r >> 6, kp = r & 63;
        arena[p * QKP + t * QKS + kp] = src[idx];
    }
    for (int idx = tid; idx < TT * DD; idx += 256)
        s_gcn[idx >> 6][idx & 63] = gcn_out[base + idx];
    unsigned* s_qkv = arena;
    __syncthreads();

    // ---- phase C1: scores (scalar)
    unsigned* s_sc = arena + SC_OFF;
    if (tid < HH * TT) {
        int h = tid / TT, t = tid % TT;
        const float scale = 0.25f;
        float qf[16];
#pragma unroll
        for (int j = 0; j < 8; ++j) {
            unsigned uq = s_qkv[0 * QKP + t * QKS + 8 * h + j];
            qf[2 * j] = bflo(uq); qf[2 * j + 1] = bfhi(uq);
        }
#pragma unroll
        for (int s2 = 0; s2 < 12; ++s2) {
            int s0 = 2 * s2;
            float d0 = 0.f, d1 = 0.f;
#pragma unroll
            for (int j = 0; j < 8; ++j) {
                unsigned ka = s_qkv[1 * QKP + s0 * QKS + 8 * h + j];
                unsigned kb = s_qkv[1 * QKP + (s0 + 1) * QKS + 8 * h + j];
                d0 += qf[2 * j] * bflo(ka) + qf[2 * j + 1] * bfhi(ka);
                d1 += qf[2 * j] * bflo(kb) + qf[2 * j + 1] * bfhi(kb);
            }
            float w0 = (s0 <= t) ? __expf(d0 * scale) : 0.f;
            float w1 = (s0 + 1 <= t) ? __expf(d1 * scale) : 0.f;
            s_sc[(h * TT + t) * 13 + s2] = packbf(w0, w1);
        }
    }
    __syncthreads();

    // ---- phase C2: normalize + PV -> packed val[24][VQS]
    unsigned* s_val = arena + VAL_OFF;
#pragma unroll
    for (int it = 0; it < 3; ++it) {
        int item = tid + it * 256;
        int h = item / 96;
        int r = item % 96;
        int t = r >> 2, d4 = r & 3;
        int kg0 = 8 * h + 2 * d4;
        float sum = 0.f, v0 = 0.f, v1 = 0.f, v2 = 0.f, v3 = 0.f;
#pragma unroll
        for (int s2 = 0; s2 < 12; ++s2) {
            unsigned uw = s_sc[(h * TT + t) * 13 + s2];
            float w0 = bflo(uw), w1 = bfhi(uw);
            sum += w0 + w1;
            unsigned ua = s_qkv[2 * QKP + (2 * s2) * QKS + kg0];
            unsigned ub = s_qkv[2 * QKP + (2 * s2) * QKS + kg0 + 1];
            v0 += w0 * bflo(ua); v1 += w0 * bfhi(ua);
            v2 += w0 * bflo(ub); v3 += w0 * bfhi(ub);
            unsigned uc = s_qkv[2 * QKP + (2 * s2 + 1) * QKS + kg0];
            unsigned ud = s_qkv[2 * QKP + (2 * s2 + 1) * QKS + kg0 + 1];
            v0 += w1 * bflo(uc); v1 += w1 * bfhi(uc);
            v2 += w1 * bflo(ud); v3 += w1 * bfhi(ud);
        }
        float inv = 1.f / sum;
        s_val[t * VQS + kg0]     = packbf(v0 * inv, v1 * inv);
        s_val[t * VQS + kg0 + 1] = packbf(v2 * inv, v3 * inv);
    }
    __syncthreads();

    // ---- phase D (MFMA): value = lrelu(val @ out_w + out_b)
    int lane = tid & 63, wid = tid >> 6;
    int cl = lane & 15, kg = lane >> 4;
    {
        f32x4 d0 = {0.f, 0.f, 0.f, 0.f}, d1 = d0;
#pragma unroll
        for (int ks = 0; ks < 4; ++ks) {
            union { uint4 u4; bf16x8 v; } a0, a1, bw;
            a0.u4 = *(const uint4*)&s_val[cl * VQS + ks * 16 + kg * 4];
            if (cl < 8) a1.u4 = *(const uint4*)&s_val[(16 + cl) * VQS + ks * 16 + kg * 4];
            else a1.u4 = make_uint4(0, 0, 0, 0);
            bw.u4 = *(const uint4*)&cw[((size_t)(wid * 4 + ks) * 64 + lane) * 8];
            d0 = __builtin_amdgcn_mfma_f32_16x16x32_bf16(a0.v, bw.v, d0, 0, 0, 0);
            d1 = __builtin_amdgcn_mfma_f32_16x16x32_bf16(a1.v, bw.v, d1, 0, 0, 0);
        }
        int col = wid * 16 + cl;
        float bias = out_b[col];
#pragma unroll
        for (int r = 0; r < 4; ++r) {
            int t = kg * 4 + r;
            float v = d0[r] + bias; v = (v >= 0.f) ? v : NEG * v;
            s_value[t][col] = v;
        }
        if (kg < 2) {
#pragma unroll
            for (int r = 0; r < 4; ++r) {
                int t = 16 + kg * 4 + r;
                float v = d1[r] + bias; v = (v >= 0.f) ? v : NEG * v;
                s_value[t][col] = v;
            }
        }
    }
    __syncthreads();

    // ---- phase E (MFMA): z = sigmoid([gcn|value] @ gate_w + gate_b); out = z*g + (1-z)*v + hidden
    {
        f32x4 g0 = {0.f, 0.f, 0.f, 0.f}, g1 = g0;
#pragma unroll
        for (int ks = 0; ks < 4; ++ks) {
            int i0 = ks * 32 + kg * 8;
            const float* src0 = (i0 < DD) ? &s_gcn[cl][i0] : &s_value[cl][i0 - DD];
            float4 lo = *(const float4*)src0;
            float4 hi = *(const float4*)(src0 + 4);
            bf16x8 a0 = pack_bf8(lo, hi);
            bf16x8 a1 = {0, 0, 0, 0, 0, 0, 0, 0};
            if (cl < 8) {
                const float* src1 = (i0 < DD) ? &s_gcn[16 + cl][i0] : &s_value[16 + cl][i0 - DD];
                float4 lo1 = *(const float4*)src1;
                float4 hi1 = *(const float4*)(src1 + 4);
                a1 = pack_bf8(lo1, hi1);
            }
            union { uint4 u4; bf16x8 v; } bw;
            bw.u4 = *(const uint4*)&cw[8192 + ((size_t)(wid * 4 + ks) * 64 + lane) * 8];
            g0 = __builtin_amdgcn_mfma_f32_16x16x32_bf16(a0, bw.v, g0, 0, 0, 0);
            g1 = __builtin_amdgcn_mfma_f32_16x16x32_bf16(a1, bw.v, g1, 0, 0, 0);
        }
        int col = wid * 16 + cl;
        float gb = gate_b[col];
#pragma unroll
        for (int r = 0; r < 4; ++r) {
            int t = kg * 4 + r;
            float z = 1.f / (1.f + __expf(-(g0[r] + gb)));
            float gv = s_gcn[t][col], vv = s_value[t][col];
            size_t ob = base + (size_t)t * DD + col;
            out[ob] = z * gv + (1.f - z) * vv + hidden[ob];
        }
        if (kg < 2) {
#pragma unroll
            for (int r = 0; r < 4; ++r) {
                int t = 16 + kg * 4 + r;
                float z = 1.f / (1.f + __expf(-(g1[r] + gb)));
                float gv = s_gcn[t][col], vv = s_value[t][col];
                size_t ob = base + (size_t)t * DD + col;
                out[ob] = z * gv + (1.f - z) * vv + hidden[ob];
            }
        }
    }
}

extern "C" void kernel_launch(void* const* d_in, const int* in_sizes, int n_in,
                              void* d_out, int out_size, void* d_ws, size_t ws_size,
                              hipStream_t stream) {
    const float* hidden   = (const float*)d_in[0];
    const float* tXin     = (const float*)d_in[1];
    const float* matrix   = (const float*)d_in[2];
    const float* gcn_w    = (const float*)d_in[3];
    const float* gcn_b    = (const float*)d_in[4];
    const float* node_emb = (const float*)d_in[5];
    const float* tproj_w  = (const float*)d_in[6];
    const float* tproj_b  = (const float*)d_in[7];
    const float* WK_      = (const float*)d_in[8];   // dict order: WK, WQ, WV
    const float* WQ_      = (const float*)d_in[9];
    const float* WV_      = (const float*)d_in[10];
    const float* out_w    = (const float*)d_in[11];
    const float* out_b    = (const float*)d_in[12];
    const float* gate_w   = (const float*)d_in[13];
    const float* gate_b   = (const float*)d_in[14];
    float* out = (float*)d_out;

    char* ws = (char*)d_ws;
    float* tfeat   = (float*)ws;                         // 512 B
    float* gcn_out = (float*)(ws + 512);                 // 15,974,400 B
    size_t off_ht  = 512 + (size_t)BB * NN * TT * DD * 4;
    size_t ht_size = (size_t)BB * TT * DD * HTM * 2 + 4096;
    size_t off_cw  = off_ht + ht_size;
    size_t off_wp  = off_cw + 32768;

    const size_t per_wp  = 3 * (size_t)E2 * E2 * 2;
    const size_t per_qkv = 3 * (size_t)TT * E2 * 2;
    long long avail = (long long)ws_size - (long long)off_wp;
    long long Ull = avail / (long long)(per_wp + per_qkv);
    int U = (Ull < 1) ? 1 : ((Ull > NNODE) ? NNODE : (int)Ull);

    unsigned short* ht_buf  = (unsigned short*)(ws + off_ht);
    unsigned short* cw_buf  = (unsigned short*)(ws + off_cw);
    unsigned short* wp_buf  = (unsigned short*)(ws + off_wp);
    unsigned short* qkv_buf = (unsigned short*)(ws + off_wp + (size_t)U * per_wp);

    k_tfeat<<<BB, DD, 0, stream>>>(tXin, tproj_w, tproj_b, tfeat);
    k_cw<<<1, 256, 0, stream>>>(out_w, gate_w, cw_buf);
    k_ht<<<dim3(BB * TT, 6), 256, 0, stream>>>(hidden, ht_buf);
    k_gcn<<<dim3(BB * TT, 6), 256, 0, stream>>>(matrix, ht_buf, gcn_w, gcn_b, gcn_out);

    for (int u0 = 0; u0 < NNODE; u0 += U) {
        int Uc = (NNODE - u0 < U) ? (NNODE - u0) : U;
        k_wp<<<dim3((Uc + 15) / 16, 48), 256, 0, stream>>>(node_emb, tfeat, WQ_, WK_, WV_,
                                                           wp_buf, u0, Uc);
        k_proj<<<Uc, 256, 0, stream>>>(hidden, tXin, wp_buf, qkv_buf, u0);
        k_attn2<<<Uc, 256, 0, stream>>>((const unsigned*)qkv_buf, hidden, cw_buf,
                                        out_b, gate_b, gcn_out, out, u0);
    }
}

// Round 13
// 337.719 us; speedup vs baseline: 4.3805x; 1.1512x over previous
//
#include <hip/hip_runtime.h>
#include <math.h>

#define BB 8
#define NN 325
#define TT 24
#define DD 64
#define HH 8
#define MM 16
#define E2 128
#define DK 16
#define NEG 0.1f
#define NNODE (BB * NN)          // 2600
#define HTM 328                  // padded m-extent of ht rows

typedef short bf16x8 __attribute__((ext_vector_type(8)));
typedef float f32x4 __attribute__((ext_vector_type(4)));

__device__ __forceinline__ unsigned short f2bf(float f) {
    union { float f; unsigned u; } v; v.f = f;
    unsigned r = v.u + 0x7fffu + ((v.u >> 16) & 1u);   // RNE
    return (unsigned short)(r >> 16);
}
__device__ __forceinline__ unsigned packbf(float a, float b) {
    return (unsigned)f2bf(a) | ((unsigned)f2bf(b) << 16);
}
__device__ __forceinline__ float bflo(unsigned u) { return __uint_as_float(u << 16); }
__device__ __forceinline__ float bfhi(unsigned u) { return __uint_as_float(u & 0xffff0000u); }

__device__ __forceinline__ bf16x8 pack_bf8(float4 lo, float4 hi) {
    bf16x8 r;
    r[0] = (short)f2bf(lo.x); r[1] = (short)f2bf(lo.y);
    r[2] = (short)f2bf(lo.z); r[3] = (short)f2bf(lo.w);
    r[4] = (short)f2bf(hi.x); r[5] = (short)f2bf(hi.y);
    r[6] = (short)f2bf(hi.z); r[7] = (short)f2bf(hi.w);
    return r;
}

// ---------------- K1: tfeat[b][m] = tanh(mean_t(tXin[b,0,t,:]) @ tproj_w + tproj_b)
__global__ void k_tfeat(const float* __restrict__ tXin, const float* __restrict__ tproj_w,
                        const float* __restrict__ tproj_b, float* __restrict__ tfeat) {
    int b = blockIdx.x;
    int d = threadIdx.x;  // 64 threads
    __shared__ float mv[DD];
    float a = 0.f;
    for (int t = 0; t < TT; ++t)
        a += tXin[((size_t)(b * NN + 0) * TT + t) * DD + d];
    mv[d] = a * (1.f / (float)TT);
    __syncthreads();
    if (d < MM) {
        float acc = tproj_b[d];
        for (int j = 0; j < DD; ++j) acc += mv[j] * tproj_w[j * MM + d];
        tfeat[b * MM + d] = tanhf(acc);
    }
}

// ---------------- K_cw: out_w/gate_w -> bf16 B-fragment layout (once, 1 block)
__global__ __launch_bounds__(256) void k_cw(const float* __restrict__ out_w,
                                            const float* __restrict__ gate_w,
                                            unsigned short* __restrict__ cw) {
    int tid = threadIdx.x;
    for (int idx = tid; idx < 8192; idx += 256) {
        int i = idx >> 6, k = idx & 63;
        int nt = k >> 4, ks = i >> 5;
        int lane = (k & 15) | (((i >> 3) & 3) << 4);
        int off = (nt * 4 + ks) * 512 + lane * 8 + (i & 7);
        cw[off] = f2bf(out_w[i * 64 + k]);
        cw[8192 + off] = f2bf(gate_w[i * 64 + k]);
    }
}

// ---------------- K_ht: ht[bt][d][m] = bf16(hidden[b][m][t][d])  (transposed, padded to HTM)
__global__ __launch_bounds__(256) void k_ht(const float* __restrict__ hidden,
                                            unsigned short* __restrict__ ht) {
    int bt = blockIdx.x;          // b*TT + t
    int b = bt / TT, t = bt % TT;
    int m0 = blockIdx.y * 64;
    __shared__ float s[64][67];
    int tid = threadIdx.x;
#pragma unroll
    for (int i = 0; i < 4; ++i) {
        int idx = tid + i * 256;
        int mm = idx >> 4, q = idx & 15;
        int m = m0 + mm;
        float4 v = make_float4(0.f, 0.f, 0.f, 0.f);
        if (m < NN) v = *(const float4*)&hidden[((size_t)(b * NN + m) * TT + t) * DD + q * 4];
        s[mm][q * 4 + 0] = v.x; s[mm][q * 4 + 1] = v.y;
        s[mm][q * 4 + 2] = v.z; s[mm][q * 4 + 3] = v.w;
    }
    __syncthreads();
    size_t obase = (size_t)bt * DD * HTM;
    int jcap = HTM - m0;
#pragma unroll
    for (int i = 0; i < 16; ++i) {
        int idx = tid + i * 256;
        int d = idx >> 6, j = idx & 63;
        if (j < jcap) ht[obase + (size_t)d * HTM + m0 + j] = f2bf(s[j][d]);
    }
}

// ---------------- K2 (MFMA): S = matrix(b,t) @ H ; gcn_out = relu(S @ gcn_w + b)
__global__ __launch_bounds__(256) void k_gcn(const float* __restrict__ matrix,
                                             const unsigned short* __restrict__ ht,
                                             const float* __restrict__ gcn_w,
                                             const float* __restrict__ gcn_b,
                                             float* __restrict__ gcn_out) {
    int bt = blockIdx.x;
    int tile = blockIdx.y;
    int b = bt / TT, t = bt % TT;
    int n0 = tile * 64;
    int tid = threadIdx.x, lane = tid & 63, wid = tid >> 6;
    int cl = lane & 15, kg = lane >> 4;

    __shared__ unsigned short s_s[64][72];    // S bf16 [n][d]
    __shared__ unsigned short s_gw[64][72];   // gw^T bf16 [e][d]

#pragma unroll
    for (int i = 0; i < 4; ++i) {
        int idx = tid + i * 256;
        int d = idx >> 4, e0 = (idx & 15) * 4;
        float4 v = *(const float4*)&gcn_w[d * DD + e0];
        s_gw[e0 + 0][d] = f2bf(v.x); s_gw[e0 + 1][d] = f2bf(v.y);
        s_gw[e0 + 2][d] = f2bf(v.z); s_gw[e0 + 3][d] = f2bf(v.w);
    }
    __syncthreads();

    const float* mrow = matrix + (size_t)bt * NN * NN;
    const unsigned short* hbase = ht + (size_t)bt * DD * HTM;
    int strip = wid * 16;
    int arow = n0 + strip + cl;
    bool avalid = arow < NN;
    const float* arp = mrow + (size_t)arow * NN;

    f32x4 acc[4];
#pragma unroll
    for (int nt = 0; nt < 4; ++nt) acc[nt] = (f32x4){0.f, 0.f, 0.f, 0.f};

#pragma unroll 1
    for (int ch = 0; ch < 5; ++ch) {
#pragma unroll
        for (int kk = 0; kk < 2; ++kk) {
            int m0 = ch * 64 + kk * 32 + kg * 8;
            bf16x8 af = {0, 0, 0, 0, 0, 0, 0, 0};
            if (avalid) {
                float4 lo, hi;
                lo.x = arp[m0];     lo.y = arp[m0 + 1]; lo.z = arp[m0 + 2]; lo.w = arp[m0 + 3];
                hi.x = arp[m0 + 4]; hi.y = arp[m0 + 5]; hi.z = arp[m0 + 6]; hi.w = arp[m0 + 7];
                af = pack_bf8(lo, hi);
            }
#pragma unroll
            for (int nt = 0; nt < 4; ++nt) {
                union { uint4 u4; bf16x8 v; } bf;
                bf.u4 = *(const uint4*)&hbase[(size_t)(nt * 16 + cl) * HTM + m0];
                acc[nt] = __builtin_amdgcn_mfma_f32_16x16x32_bf16(af, bf.v, acc[nt], 0, 0, 0);
            }
        }
    }
    {
        int m0 = 320 + kg * 8;
        float v[8];
#pragma unroll
        for (int j = 0; j < 8; ++j)
            v[j] = (avalid && (m0 + j) < NN) ? arp[m0 + j] : 0.f;
        bf16x8 af = pack_bf8(make_float4(v[0], v[1], v[2], v[3]),
                             make_float4(v[4], v[5], v[6], v[7]));
#pragma unroll
        for (int nt = 0; nt < 4; ++nt) {
            union { uint4 u4; bf16x8 v4; } bf;
            bf.u4 = *(const uint4*)&hbase[(size_t)(nt * 16 + cl) * HTM + m0];
            acc[nt] = __builtin_amdgcn_mfma_f32_16x16x32_bf16(af, bf.v4, acc[nt], 0, 0, 0);
        }
    }

#pragma unroll
    for (int nt = 0; nt < 4; ++nt)
#pragma unroll
        for (int r = 0; r < 4; ++r)
            s_s[strip + kg * 4 + r][nt * 16 + cl] = f2bf(acc[nt][r]);

    f32x4 g[4];
#pragma unroll
    for (int nt = 0; nt < 4; ++nt) g[nt] = (f32x4){0.f, 0.f, 0.f, 0.f};
#pragma unroll
    for (int kk = 0; kk < 2; ++kk) {
        union { uint4 u4; bf16x8 v; } sa;
        sa.u4 = *(const uint4*)&s_s[strip + cl][kk * 32 + kg * 8];
#pragma unroll
        for (int nt = 0; nt < 4; ++nt) {
            union { uint4 u4; bf16x8 v; } bf;
            bf.u4 = *(const uint4*)&s_gw[nt * 16 + cl][kk * 32 + kg * 8];
            g[nt] = __builtin_amdgcn_mfma_f32_16x16x32_bf16(sa.v, bf.v, g[nt], 0, 0, 0);
        }
    }

#pragma unroll
    for (int nt = 0; nt < 4; ++nt) {
        float bias = gcn_b[nt * 16 + cl];
#pragma unroll
        for (int r = 0; r < 4; ++r) {
            int n = n0 + strip + kg * 4 + r;
            if (n < NN) {
                float v = g[nt][r] + bias;
                v = (v > 0.f) ? v : 0.f;
                gcn_out[((size_t)(b * NN + n) * TT + t) * DD + nt * 16 + cl] = v;
            }
        }
    }
}

// ---------------- K3a: Wp = sum_m e[m]*W[m], bf16 in MFMA B-fragment-major layout.
// LDS staging layout padded: per-nt stride 136 u16 (272 B == 32 mod 128) ->
// store-phase banks (4nt+16t3)%32 = 2-way max (free, m136); read uint4 gets +4-bank
// rotation per nt. 136 = 17*8 keeps uint4 alignment. (R12 had stride 128 -> 16-way,
// 59M conflict cycles = ~97 us/CU.)
__global__ __launch_bounds__(256) void k_wp(
    const float* __restrict__ node_emb, const float* __restrict__ tfeat,
    const float* __restrict__ WQ, const float* __restrict__ WK, const float* __restrict__ WV,
    unsigned short* __restrict__ wp, int u0, int Uc) {
    int un0 = blockIdx.x * 16;
    int chunk = blockIdx.y;                 // 0..47
    int p = chunk >> 4;                     // 0=Q 1=K 2=V
    int c = chunk & 15;                     // i-block
    int off = c << 10;
    int tid = threadIdx.x;
    const float* __restrict__ W = (p == 0) ? WQ : ((p == 1) ? WK : WV);

    __shared__ float s_e[16][MM];
    __shared__ __align__(16) unsigned short s_out[16][1088];   // 8 nt x 136 (padded), 34 KB

    {
        int nn = tid >> 4, m = tid & 15;
        int us = un0 + nn;
        float e = 0.f;
        if (us < Uc) {
            int u = u0 + us;
            int b = u / NN, n = u % NN;
            e = node_emb[n * MM + m] * tfeat[b * MM + m];
        }
        s_e[nn][m] = e;
    }
    __syncthreads();

    int j = off + tid * 4;
    int k0 = j & 127;
    float4 acc[16];
#pragma unroll
    for (int nn = 0; nn < 16; ++nn) acc[nn] = make_float4(0.f, 0.f, 0.f, 0.f);
#pragma unroll
    for (int m = 0; m < MM; ++m) {
        float4 w = *(const float4*)&W[(size_t)m * 16384 + j];
#pragma unroll
        for (int nn = 0; nn < 16; ++nn) {
            float e = s_e[nn][m];
            acc[nn].x += e * w.x; acc[nn].y += e * w.y;
            acc[nn].z += e * w.z; acc[nn].w += e * w.w;
        }
    }

    int nt = k0 >> 4;
    int jf = tid >> 5;
    int lb = nt * 136 + jf;                 // padded stride
    int s0 = (k0 & 15) * 8;
#pragma unroll
    for (int nn = 0; nn < 16; ++nn) {
        s_out[nn][lb + s0]      = f2bf(acc[nn].x);
        s_out[nn][lb + s0 + 8]  = f2bf(acc[nn].y);
        s_out[nn][lb + s0 + 16] = f2bf(acc[nn].z);
        s_out[nn][lb + s0 + 24] = f2bf(acc[nn].w);
    }
    __syncthreads();

    int ks = c >> 2, L = c & 3;
    size_t gbase = (size_t)p * 16384 + (size_t)ks * 512 + (size_t)L * 128;
#pragma unroll
    for (int ii = 0; ii < 8; ++ii) {
        int o = ii * 256 + tid;
        int node = o >> 7, r = o & 127;
        int ntw = r >> 4, w = r & 15;
        int us = un0 + node;
        if (us < Uc) {
            uint4 v = *(const uint4*)&s_out[node][ntw * 136 + w * 8];
            *(uint4*)&wp[(size_t)us * 49152 + gbase + (size_t)ntw * 2048 + w * 8] = v;
        }
    }
}

// ---------------- K3b: per node MFMA proj -> lrelu -> qkv bf16 to workspace.
__global__ __launch_bounds__(256) void k_proj(
    const float* __restrict__ hidden, const float* __restrict__ tXin,
    const unsigned short* __restrict__ wp, unsigned short* __restrict__ qkv,
    int u0) {
    int us = blockIdx.x;
    int u = u0 + us;
    int tid = threadIdx.x;
    int lane = tid & 63, wid = tid >> 6;
    int trow = lane & 15, kgrp = lane >> 4;

    size_t base = (size_t)u * TT * DD;

    bf16x8 afrag[2][4];
#pragma unroll
    for (int mt = 0; mt < 2; ++mt) {
        int t = mt * 16 + trow;
        bool valid = (t < TT);
#pragma unroll
        for (int ks = 0; ks < 4; ++ks) {
            int i0 = ks * 32 + kgrp * 8;
            float4 lo = make_float4(0.f, 0.f, 0.f, 0.f), hi = lo;
            if (valid) {
                const float* src = (i0 < DD) ? &hidden[base + t * DD + i0]
                                             : &tXin[base + t * DD + (i0 - DD)];
                lo = *(const float4*)src;
                hi = *(const float4*)(src + 4);
            }
            afrag[mt][ks] = pack_bf8(lo, hi);
        }
    }

    const unsigned short* wbase = wp + (size_t)us * 49152;
    unsigned short* qbase = qkv + (size_t)us * (3 * TT * E2);
    int rowg = kgrp * 4;
    int col0 = wid * 16 + trow;
    int col1 = (wid + 4) * 16 + trow;
#pragma unroll 1
    for (int p = 0; p < 3; ++p) {
        f32x4 acc00 = {0.f, 0.f, 0.f, 0.f}, acc01 = acc00, acc10 = acc00, acc11 = acc00;
#pragma unroll
        for (int ks = 0; ks < 4; ++ks) {
            union { uint4 u4; bf16x8 v; } c0, c1;
            c0.u4 = *(const uint4*)(wbase + (size_t)p * 16384 + (((wid) * 4 + ks) * 64 + lane) * 8);
            c1.u4 = *(const uint4*)(wbase + (size_t)p * 16384 + (((wid + 4) * 4 + ks) * 64 + lane) * 8);
            acc00 = __builtin_amdgcn_mfma_f32_16x16x32_bf16(afrag[0][ks], c0.v, acc00, 0, 0, 0);
            acc10 = __builtin_amdgcn_mfma_f32_16x16x32_bf16(afrag[1][ks], c0.v, acc10, 0, 0, 0);
            acc01 = __builtin_amdgcn_mfma_f32_16x16x32_bf16(afrag[0][ks], c1.v, acc01, 0, 0, 0);
            acc11 = __builtin_amdgcn_mfma_f32_16x16x32_bf16(afrag[1][ks], c1.v, acc11, 0, 0, 0);
        }
#pragma unroll
        for (int r = 0; r < 4; ++r) {
            int t = rowg + r;
            float v0 = acc00[r]; v0 = (v0 >= 0.f) ? v0 : NEG * v0;
            float v1 = acc01[r]; v1 = (v1 >= 0.f) ? v1 : NEG * v1;
            qbase[(p * TT + t) * E2 + col0] = f2bf(v0);
            qbase[(p * TT + t) * E2 + col1] = f2bf(v1);
        }
        if (rowg < 8) {
#pragma unroll
            for (int r = 0; r < 4; ++r) {
                int t = 16 + rowg + r;
                float v0 = acc10[r]; v0 = (v0 >= 0.f) ? v0 : NEG * v0;
                float v1 = acc11[r]; v1 = (v1 >= 0.f) ? v1 : NEG * v1;
                qbase[(p * TT + t) * E2 + col0] = f2bf(v0);
                qbase[(p * TT + t) * E2 + col1] = f2bf(v1);
            }
        }
    }
}

// ---------------- K3c: per node: attention (scalar C1/C2) + MFMA out-proj/gate + residual
#define QKS 66
#define QKP (TT * QKS)
#define SC_OFF 4752
#define VAL_OFF 7248
#define VQS 68
__global__ __launch_bounds__(256) void k_attn2(
    const unsigned* __restrict__ qkv, const float* __restrict__ hidden,
    const unsigned short* __restrict__ cw,
    const float* __restrict__ out_b, const float* __restrict__ gate_b,
    const float* __restrict__ gcn_out, float* __restrict__ out,
    int u0) {
    int us = blockIdx.x;
    int u = u0 + us;
    int tid = threadIdx.x;

    __shared__ __align__(16) unsigned arena[8880];
    __shared__ float s_gcn[TT][VQS];
    __shared__ float s_value[TT][VQS];

    size_t base = (size_t)u * TT * DD;

    const unsigned* src = qkv + (size_t)us * (3 * TT * 64);
    for (int idx = tid; idx < 3 * TT * 64; idx += 256) {
        int p = idx / (TT * 64);
        int r = idx % (TT * 64);
        int t = r >> 6, kp = r & 63;
        arena[p * QKP + t * QKS + kp] = src[idx];
    }
    for (int idx = tid; idx < TT * DD; idx += 256)
        s_gcn[idx >> 6][idx & 63] = gcn_out[base + idx];
    unsigned* s_qkv = arena;
    __syncthreads();

    // ---- phase C1: scores (scalar)
    unsigned* s_sc = arena + SC_OFF;
    if (tid < HH * TT) {
        int h = tid / TT, t = tid % TT;
        const float scale = 0.25f;
        float qf[16];
#pragma unroll
        for (int j = 0; j < 8; ++j) {
            unsigned uq = s_qkv[0 * QKP + t * QKS + 8 * h + j];
            qf[2 * j] = bflo(uq); qf[2 * j + 1] = bfhi(uq);
        }
#pragma unroll
        for (int s2 = 0; s2 < 12; ++s2) {
            int s0 = 2 * s2;
            float d0 = 0.f, d1 = 0.f;
#pragma unroll
            for (int j = 0; j < 8; ++j) {
                unsigned ka = s_qkv[1 * QKP + s0 * QKS + 8 * h + j];
                unsigned kb = s_qkv[1 * QKP + (s0 + 1) * QKS + 8 * h + j];
                d0 += qf[2 * j] * bflo(ka) + qf[2 * j + 1] * bfhi(ka);
                d1 += qf[2 * j] * bflo(kb) + qf[2 * j + 1] * bfhi(kb);
            }
            float w0 = (s0 <= t) ? __expf(d0 * scale) : 0.f;
            float w1 = (s0 + 1 <= t) ? __expf(d1 * scale) : 0.f;
            s_sc[(h * TT + t) * 13 + s2] = packbf(w0, w1);
        }
    }
    __syncthreads();

    // ---- phase C2: normalize + PV -> packed val[24][VQS]
    unsigned* s_val = arena + VAL_OFF;
#pragma unroll
    for (int it = 0; it < 3; ++it) {
        int item = tid + it * 256;
        int h = item / 96;
        int r = item % 96;
        int t = r >> 2, d4 = r & 3;
        int kg0 = 8 * h + 2 * d4;
        float sum = 0.f, v0 = 0.f, v1 = 0.f, v2 = 0.f, v3 = 0.f;
#pragma unroll
        for (int s2 = 0; s2 < 12; ++s2) {
            unsigned uw = s_sc[(h * TT + t) * 13 + s2];
            float w0 = bflo(uw), w1 = bfhi(uw);
            sum += w0 + w1;
            unsigned ua = s_qkv[2 * QKP + (2 * s2) * QKS + kg0];
            unsigned ub = s_qkv[2 * QKP + (2 * s2) * QKS + kg0 + 1];
            v0 += w0 * bflo(ua); v1 += w0 * bfhi(ua);
            v2 += w0 * bflo(ub); v3 += w0 * bfhi(ub);
            unsigned uc = s_qkv[2 * QKP + (2 * s2 + 1) * QKS + kg0];
            unsigned ud = s_qkv[2 * QKP + (2 * s2 + 1) * QKS + kg0 + 1];
            v0 += w1 * bflo(uc); v1 += w1 * bfhi(uc);
            v2 += w1 * bflo(ud); v3 += w1 * bfhi(ud);
        }
        float inv = 1.f / sum;
        s_val[t * VQS + kg0]     = packbf(v0 * inv, v1 * inv);
        s_val[t * VQS + kg0 + 1] = packbf(v2 * inv, v3 * inv);
    }
    __syncthreads();

    // ---- phase D (MFMA): value = lrelu(val @ out_w + out_b)
    int lane = tid & 63, wid = tid >> 6;
    int cl = lane & 15, kg = lane >> 4;
    {
        f32x4 d0 = {0.f, 0.f, 0.f, 0.f}, d1 = d0;
#pragma unroll
        for (int ks = 0; ks < 4; ++ks) {
            union { uint4 u4; bf16x8 v; } a0, a1, bw;
            a0.u4 = *(const uint4*)&s_val[cl * VQS + ks * 16 + kg * 4];
            if (cl < 8) a1.u4 = *(const uint4*)&s_val[(16 + cl) * VQS + ks * 16 + kg * 4];
            else a1.u4 = make_uint4(0, 0, 0, 0);
            bw.u4 = *(const uint4*)&cw[((size_t)(wid * 4 + ks) * 64 + lane) * 8];
            d0 = __builtin_amdgcn_mfma_f32_16x16x32_bf16(a0.v, bw.v, d0, 0, 0, 0);
            d1 = __builtin_amdgcn_mfma_f32_16x16x32_bf16(a1.v, bw.v, d1, 0, 0, 0);
        }
        int col = wid * 16 + cl;
        float bias = out_b[col];
#pragma unroll
        for (int r = 0; r < 4; ++r) {
            int t = kg * 4 + r;
            float v = d0[r] + bias; v = (v >= 0.f) ? v : NEG * v;
            s_value[t][col] = v;
        }
        if (kg < 2) {
#pragma unroll
            for (int r = 0; r < 4; ++r) {
                int t = 16 + kg * 4 + r;
                float v = d1[r] + bias; v = (v >= 0.f) ? v : NEG * v;
                s_value[t][col] = v;
            }
        }
    }
    __syncthreads();

    // ---- phase E (MFMA): z = sigmoid([gcn|value] @ gate_w + gate_b); out = z*g + (1-z)*v + hidden
    {
        f32x4 g0 = {0.f, 0.f, 0.f, 0.f}, g1 = g0;
#pragma unroll
        for (int ks = 0; ks < 4; ++ks) {
            int i0 = ks * 32 + kg * 8;
            const float* src0 = (i0 < DD) ? &s_gcn[cl][i0] : &s_value[cl][i0 - DD];
            float4 lo = *(const float4*)src0;
            float4 hi = *(const float4*)(src0 + 4);
            bf16x8 a0 = pack_bf8(lo, hi);
            bf16x8 a1 = {0, 0, 0, 0, 0, 0, 0, 0};
            if (cl < 8) {
                const float* src1 = (i0 < DD) ? &s_gcn[16 + cl][i0] : &s_value[16 + cl][i0 - DD];
                float4 lo1 = *(const float4*)src1;
                float4 hi1 = *(const float4*)(src1 + 4);
                a1 = pack_bf8(lo1, hi1);
            }
            union { uint4 u4; bf16x8 v; } bw;
            bw.u4 = *(const uint4*)&cw[8192 + ((size_t)(wid * 4 + ks) * 64 + lane) * 8];
            g0 = __builtin_amdgcn_mfma_f32_16x16x32_bf16(a0, bw.v, g0, 0, 0, 0);
            g1 = __builtin_amdgcn_mfma_f32_16x16x32_bf16(a1, bw.v, g1, 0, 0, 0);
        }
        int col = wid * 16 + cl;
        float gb = gate_b[col];
#pragma unroll
        for (int r = 0; r < 4; ++r) {
            int t = kg * 4 + r;
            float z = 1.f / (1.f + __expf(-(g0[r] + gb)));
            float gv = s_gcn[t][col], vv = s_value[t][col];
            size_t ob = base + (size_t)t * DD + col;
            out[ob] = z * gv + (1.f - z) * vv + hidden[ob];
        }
        if (kg < 2) {
#pragma unroll
            for (int r = 0; r < 4; ++r) {
                int t = 16 + kg * 4 + r;
                float z = 1.f / (1.f + __expf(-(g1[r] + gb)));
                float gv = s_gcn[t][col], vv = s_value[t][col];
                size_t ob = base + (size_t)t * DD + col;
                out[ob] = z * gv + (1.f - z) * vv + hidden[ob];
            }
        }
    }
}

extern "C" void kernel_launch(void* const* d_in, const int* in_sizes, int n_in,
                              void* d_out, int out_size, void* d_ws, size_t ws_size,
                              hipStream_t stream) {
    const float* hidden   = (const float*)d_in[0];
    const float* tXin     = (const float*)d_in[1];
    const float* matrix   = (const float*)d_in[2];
    const float* gcn_w    = (const float*)d_in[3];
    const float* gcn_b    = (const float*)d_in[4];
    const float* node_emb = (const float*)d_in[5];
    const float* tproj_w  = (const float*)d_in[6];
    const float* tproj_b  = (const float*)d_in[7];
    const float* WK_      = (const float*)d_in[8];   // dict order: WK, WQ, WV
    const float* WQ_      = (const float*)d_in[9];
    const float* WV_      = (const float*)d_in[10];
    const float* out_w    = (const float*)d_in[11];
    const float* out_b    = (const float*)d_in[12];
    const float* gate_w   = (const float*)d_in[13];
    const float* gate_b   = (const float*)d_in[14];
    float* out = (float*)d_out;

    char* ws = (char*)d_ws;
    float* tfeat   = (float*)ws;                         // 512 B
    float* gcn_out = (float*)(ws + 512);                 // 15,974,400 B
    size_t off_ht  = 512 + (size_t)BB * NN * TT * DD * 4;
    size_t ht_size = (size_t)BB * TT * DD * HTM * 2 + 4096;
    size_t off_cw  = off_ht + ht_size;
    size_t off_wp  = off_cw + 32768;

    const size_t per_wp  = 3 * (size_t)E2 * E2 * 2;
    const size_t per_qkv = 3 * (size_t)TT * E2 * 2;
    long long avail = (long long)ws_size - (long long)off_wp;
    long long Ull = avail / (long long)(per_wp + per_qkv);
    int U = (Ull < 1) ? 1 : ((Ull > NNODE) ? NNODE : (int)Ull);

    unsigned short* ht_buf  = (unsigned short*)(ws + off_ht);
    unsigned short* cw_buf  = (unsigned short*)(ws + off_cw);
    unsigned short* wp_buf  = (unsigned short*)(ws + off_wp);
    unsigned short* qkv_buf = (unsigned short*)(ws + off_wp + (size_t)U * per_wp);

    k_tfeat<<<BB, DD, 0, stream>>>(tXin, tproj_w, tproj_b, tfeat);
    k_cw<<<1, 256, 0, stream>>>(out_w, gate_w, cw_buf);
    k_ht<<<dim3(BB * TT, 6), 256, 0, stream>>>(hidden, ht_buf);
    k_gcn<<<dim3(BB * TT, 6), 256, 0, stream>>>(matrix, ht_buf, gcn_w, gcn_b, gcn_out);

    for (int u0 = 0; u0 < NNODE; u0 += U) {
        int Uc = (NNODE - u0 < U) ? (NNODE - u0) : U;
        k_wp<<<dim3((Uc + 15) / 16, 48), 256, 0, stream>>>(node_emb, tfeat, WQ_, WK_, WV_,
                                                           wp_buf, u0, Uc);
        k_proj<<<Uc, 256, 0, stream>>>(hidden, tXin, wp_buf, qkv_buf, u0);
        k_attn2<<<Uc, 256, 0, stream>>>((const unsigned*)qkv_buf, hidden, cw_buf,
                                        out_b, gate_b, gcn_out, out, u0);
    }
}